// Round 13
// baseline (927.242 us; speedup 1.0000x reference)
//
#include <hip/hip_runtime.h>

typedef unsigned short u16;
typedef unsigned int u32;
typedef unsigned long long u64;

typedef __attribute__((ext_vector_type(8))) short bf16x8;
typedef __attribute__((ext_vector_type(4))) float f32x4;

__device__ __forceinline__ u16 f2b(float f) {
  u32 u = __float_as_uint(f);
  u32 r = (u + 0x7fffu + ((u >> 16) & 1u)) >> 16;  // RNE
  return (u16)r;
}
__device__ __forceinline__ float b2f(u16 h) {
  return __uint_as_float(((u32)h) << 16);
}
__device__ __forceinline__ float key2f(u32 k) {
  u16 kk = (u16)k;
  u16 bits = (kk & 0x8000) ? (u16)(kk ^ 0x8000) : (u16)(~kk);
  return b2f(bits);
}
__device__ __forceinline__ u64 makekey(float f, int i) {
  u32 u = __float_as_uint(f);
  u = (u & 0x80000000u) ? ~u : (u | 0x80000000u);
  return ((u64)u << 32) | (u32)i;
}

__device__ __forceinline__ void gload16(const void* g, void* l) {
  __builtin_amdgcn_global_load_lds((const __attribute__((address_space(1))) void*)g,
                                   (__attribute__((address_space(3))) void*)l, 16, 0, 0);
}

// ---------------- fp32 -> bf16 convert (8 elems/thread) --------------------
__global__ __launch_bounds__(256) void conv_k(const float* __restrict__ s,
                                              u16* __restrict__ d, int n8) {
  int i = blockIdx.x * 256 + threadIdx.x;
  if (i >= n8) return;
  const float4* s4 = reinterpret_cast<const float4*>(s);
  float4 f0 = s4[i * 2], f1 = s4[i * 2 + 1];
  __align__(16) u16 t[8];
  t[0] = f2b(f0.x); t[1] = f2b(f0.y); t[2] = f2b(f0.z); t[3] = f2b(f0.w);
  t[4] = f2b(f1.x); t[5] = f2b(f1.y); t[6] = f2b(f1.z); t[7] = f2b(f1.w);
  reinterpret_cast<uint4*>(d)[i] = *reinterpret_cast<uint4*>(t);
}

// -------- transpose+convert W (K x Nc fp32) -> Wt (Nc x K bf16), LDS-tiled -
__global__ __launch_bounds__(256) void convt_k(const float* __restrict__ W,
                                               u16* __restrict__ Wt, int K, int Nc) {
  __shared__ float t[32][33];
  int k0 = blockIdx.x * 32, n0 = blockIdx.y * 32;
  int c = threadIdx.x & 31, r4 = threadIdx.x >> 5;
#pragma unroll
  for (int i = 0; i < 4; ++i) {
    int r = r4 + i * 8;
    t[r][c] = W[(size_t)(k0 + r) * Nc + n0 + c];
  }
  __syncthreads();
#pragma unroll
  for (int i = 0; i < 4; ++i) {
    int r = r4 + i * 8;
    Wt[(size_t)(n0 + r) * K + k0 + c] = f2b(t[c][r]);
  }
}

// ============ m201-style 256x256 8-phase MFMA GEMM (C = A * B^T) ===========
// BK=64, LDS 128KB: LA/LB[2buf][2half][128][64]. 8 waves (2M x 4N); per-wave
// out 128x64 as 2x2 quadrants of 64x32. Per phase: {ds_reads (12/4/8/0) |
// 1 half-tile stage (2 gload16/thr) | bar | lgkmcnt(0) | setprio 16 MFMA |
// [vmcnt(2) at P3/P7] | bar}. Stage ledger: buf fully reg-captured after its
// 2nd read phase -> stages P3-P6 (buf0<-T+2) / P7,P0-P2 (buf1<-T+3) are WAR-
// safe; vmcnt(2) drains exactly the 4 halves the next compute needs.
// MODE 0: proj tanh(v+bias[col]); z selects (A2,B2,bias2,out2). MODE 1: score
// v*rs[row]*cs[col].
template <int MODE>
__global__ __launch_bounds__(512, 2) void mmT_k(
    const u16* __restrict__ A, const u16* __restrict__ B, int K, int Mbase,
    int mtiles, const float* __restrict__ rs, const float* __restrict__ cs,
    const float* __restrict__ bias, u16* __restrict__ out, int ldc,
    const u16* A2, const u16* B2, const float* bias2, u16* out2) {
  if (MODE == 0 && blockIdx.z) { A = A2; B = B2; bias = bias2; out = out2; }
  __shared__ u16 LA[2][2][128][64];
  __shared__ u16 LB[2][2][128][64];
  int tid = threadIdx.x, lane = tid & 63, wid = tid >> 6;
  int wm = wid >> 2, wn = wid & 3;
  int rsel = lane & 15, rgrp = lane >> 4;

  int nwg = gridDim.x * gridDim.y;
  int fid = blockIdx.y * gridDim.x + blockIdx.x;
  int chunk = nwg >> 3;
  int s = (fid & 7) * chunk + (fid >> 3);  // XCD remap (nwg%8==0)
  int mtile = s % mtiles, ntile = s / mtiles;
  int mrow0 = Mbase + mtile * 256;
  int ncol0 = ntile * 256;

  // staging: thread covers chunks (wid*2+l)*64+lane of a 128x(64u16) half
  int srow_[2], scsw_[2];
#pragma unroll
  for (int l = 0; l < 2; ++l) {
    int ci = (wid * 2 + l) * 64 + lane;
    srow_[l] = ci >> 3;
    scsw_[l] = (ci & 7) ^ ((srow_[l] >> 1) & 7);  // pre-swizzled src chunk
  }

  auto stageH = [&](int buf, int mat, int half, int kt) {
#pragma unroll
    for (int l = 0; l < 2; ++l) {
      int grow = (mat ? ncol0 : mrow0) + half * 128 + srow_[l];
      const u16* g = (mat ? B : A) + (size_t)grow * K + kt * 64 + scsw_[l] * 8;
      u16* d = (mat ? &LB[buf][half][0][0] : &LA[buf][half][0][0]) +
               (wid * 2 + l) * 512;  // wave-uniform; HW adds lane*16B
      gload16(g, d);
    }
  };

  f32x4 acc[2][4][2][2] = {};  // [qr][mf][qc][nf]
  bf16x8 afr[4][2], bfr[2][2][2];

  auto rdA = [&](int buf, int qr) {
#pragma unroll
    for (int mf = 0; mf < 4; ++mf)
#pragma unroll
      for (int kk = 0; kk < 2; ++kk) {
        int row = qr * 64 + mf * 16 + rsel;
        int ch = (kk * 4 + rgrp) ^ ((row >> 1) & 7);
        afr[mf][kk] = *reinterpret_cast<const bf16x8*>(&LA[buf][wm][row][ch * 8]);
      }
  };
  auto rdB = [&](int buf, int qc) {
#pragma unroll
    for (int nf = 0; nf < 2; ++nf)
#pragma unroll
      for (int kk = 0; kk < 2; ++kk) {
        int col = wn * 64 + qc * 32 + nf * 16 + rsel;
        int half = col >> 7, row = col & 127;
        int ch = (kk * 4 + rgrp) ^ ((row >> 1) & 7);
        bfr[qc][nf][kk] = *reinterpret_cast<const bf16x8*>(&LB[buf][half][row][ch * 8]);
      }
  };

#define MMQ(QR, QC)                                                            \
  _Pragma("unroll") for (int kk = 0; kk < 2; ++kk)                             \
      _Pragma("unroll") for (int mf = 0; mf < 4; ++mf)                         \
          _Pragma("unroll") for (int nf = 0; nf < 2; ++nf)                     \
              acc[QR][mf][QC][nf] = __builtin_amdgcn_mfma_f32_16x16x32_bf16(   \
                  afr[mf][kk], bfr[QC][nf][kk], acc[QR][mf][QC][nf], 0, 0, 0);

#define PH(BUF, RD, SB, SMAT, SHALF, ST, DOWAIT, QR, QC)                       \
  {                                                                            \
    if (RD == 0) { rdA(BUF, 0); rdB(BUF, 0); }                                 \
    else if (RD == 1) rdB(BUF, 1);                                             \
    else if (RD == 2) rdA(BUF, 1);                                             \
    stageH(SB, SMAT, SHALF, ST);                                               \
    __builtin_amdgcn_s_barrier();                                              \
    asm volatile("s_waitcnt lgkmcnt(0)" ::: "memory");                         \
    __builtin_amdgcn_s_setprio(1);                                             \
    MMQ(QR, QC)                                                                \
    __builtin_amdgcn_s_setprio(0);                                             \
    if (DOWAIT) asm volatile("s_waitcnt vmcnt(2)" ::: "memory");               \
    __builtin_amdgcn_s_barrier();                                              \
  }

  int nkt = K / 64;  // >= 2, even
  // prologue: buf0 <- tile0 (A0,A1,B0,B1); buf1.A0 <- tile1 (acts as P7(-1))
  stageH(0, 0, 0, 0); stageH(0, 0, 1, 0); stageH(0, 1, 0, 0); stageH(0, 1, 1, 0);
  stageH(1, 0, 0, 1);
  asm volatile("s_waitcnt vmcnt(2)" ::: "memory");  // tile0's 8 loads done
  __builtin_amdgcn_s_barrier();

  for (int j = 0; j < nkt / 2; ++j) {
    int T1 = 2 * j + 1;
    int T2 = (2 * j + 2 < nkt) ? 2 * j + 2 : nkt - 1;  // clamped: dead writes
    int T3 = (2 * j + 3 < nkt) ? 2 * j + 3 : nkt - 1;
    PH(0, 0, 1, 0, 1, T1, 0, 0, 0)  // P0: b0 q(0,0); stage b1.A1<-T1
    PH(0, 1, 1, 1, 0, T1, 0, 0, 1)  // P1: b0 q(0,1); stage b1.B0<-T1
    PH(0, 2, 1, 1, 1, T1, 0, 1, 1)  // P2: b0 q(1,1); stage b1.B1<-T1
    PH(0, 3, 0, 0, 0, T2, 1, 1, 0)  // P3: b0 q(1,0); stage b0.A0<-T2; WAIT
    PH(1, 0, 0, 0, 1, T2, 0, 0, 0)  // P4: b1 q(0,0); stage b0.A1<-T2
    PH(1, 1, 0, 1, 0, T2, 0, 0, 1)  // P5: b1 q(0,1); stage b0.B0<-T2
    PH(1, 2, 0, 1, 1, T2, 0, 1, 1)  // P6: b1 q(1,1); stage b0.B1<-T2
    PH(1, 3, 1, 0, 0, T3, 1, 1, 0)  // P7: b1 q(1,0); stage b1.A0<-T3; WAIT
  }
#undef PH
#undef MMQ

#pragma unroll
  for (int qr = 0; qr < 2; ++qr)
#pragma unroll
    for (int mf = 0; mf < 4; ++mf)
#pragma unroll
      for (int qc = 0; qc < 2; ++qc)
#pragma unroll
        for (int nf = 0; nf < 2; ++nf)
#pragma unroll
          for (int rr = 0; rr < 4; ++rr) {
            int rl = mtile * 256 + wm * 128 + qr * 64 + mf * 16 + rgrp * 4 + rr;
            int cl = ncol0 + wn * 64 + qc * 32 + nf * 16 + rsel;
            float v = acc[qr][mf][qc][nf][rr];
            if (MODE == 1) v *= rs[Mbase + rl] * cs[cl];
            else v = tanhf(v + bias[cl]);
            out[(size_t)rl * ldc + cl] = f2b(v);
          }
}

// ---------------- unified bf16 MFMA GEMM: C = A * B^T ----------------------
// 2-phase dbuf. MODE 2: feat (gather, bias+relu, f32+bf16). MODE 3: vu.
#define TILE 128
#define BK 32

template <int MODE>
__global__ __launch_bounds__(256) void gemm2_k(
    const u16* __restrict__ Abf, const u16* __restrict__ Bbf, int lda, int ldb,
    int K, int Mreal, const float* __restrict__ bias,
    const u32* __restrict__ gidx, float* __restrict__ outf,
    u16* __restrict__ outb, int ldc,
    const u16* Abf2, const u16* Bbf2, const float* bias2,
    float* outf2, u16* outb2) {
  if (blockIdx.z) {
    if (Abf2) Abf = Abf2;
    if (Bbf2) Bbf = Bbf2;
    if (bias2) bias = bias2;
    if (outf2) outf = outf2;
    if (outb2) outb = outb2;
  }
  __shared__ u16 As[2][TILE][BK];
  __shared__ u16 Bs[2][TILE][BK];
  int tid = threadIdx.x, lane = tid & 63, wid = tid >> 6;
  int mt = blockIdx.x, nt2 = blockIdx.y;
  int row0 = (wid >> 1) * 64, col0 = (wid & 1) * 64;

  int scol = (lane & 3) * 8;
  const u16* gA[2];
  const u16* gB[2];
#pragma unroll
  for (int h = 0; h < 2; ++h) {
    int rA = (wid * 2 + h) * 16 + (lane >> 2);
    int grow = mt * TILE + rA;
    int arow;
    if (MODE == 2) arow = (int)gidx[grow < Mreal ? grow : 0];
    else arow = grow;
    gA[h] = Abf + (size_t)arow * lda + scol;
    int bcol = nt2 * TILE + rA;
    gB[h] = Bbf + (size_t)bcol * ldb + scol;
  }

  auto stage = [&](int buf, int kt) {
#pragma unroll
    for (int h = 0; h < 2; ++h) {
      gload16(gA[h] + kt, &As[buf][(wid * 2 + h) * 16][0]);
      gload16(gB[h] + kt, &Bs[buf][(wid * 2 + h) * 16][0]);
    }
  };

  f32x4 acc[4][4] = {};
  int k8 = 8 * (lane >> 4), rsel = lane & 15;
  int nkt = K / BK;

  stage(0, 0);
  __syncthreads();
  int cur = 0;
  for (int t = 0; t < nkt; ++t) {
    if (t + 1 < nkt) stage(cur ^ 1, (t + 1) * BK);
    bf16x8 a[4], b[4];
#pragma unroll
    for (int m = 0; m < 4; ++m)
      a[m] = *reinterpret_cast<const bf16x8*>(&As[cur][row0 + m * 16 + rsel][k8]);
#pragma unroll
    for (int n = 0; n < 4; ++n)
      b[n] = *reinterpret_cast<const bf16x8*>(&Bs[cur][col0 + n * 16 + rsel][k8]);
    __builtin_amdgcn_s_setprio(1);
#pragma unroll
    for (int m = 0; m < 4; ++m)
#pragma unroll
      for (int n = 0; n < 4; ++n)
        acc[m][n] = __builtin_amdgcn_mfma_f32_16x16x32_bf16(a[m], b[n], acc[m][n], 0, 0, 0);
    __builtin_amdgcn_s_setprio(0);
    __syncthreads();
    cur ^= 1;
  }

  int rgrp = lane >> 4, csel = lane & 15;
#pragma unroll
  for (int m = 0; m < 4; ++m)
#pragma unroll
    for (int n = 0; n < 4; ++n)
#pragma unroll
      for (int r = 0; r < 4; ++r) {
        int grow = mt * TILE + row0 + m * 16 + rgrp * 4 + r;
        int gcol = nt2 * TILE + col0 + n * 16 + csel;
        float v = acc[m][n][r];
        if (MODE == 2) {
          if (grow < Mreal) {
            v = fmaxf(v + bias[gcol], 0.f);
            outf[(size_t)grow * ldc + gcol] = v;
            outb[(size_t)grow * ldc + gcol] = f2b(v);
          }
        } else {
          if (grow < Mreal) outf[(size_t)grow * ldc + gcol] = v + bias[gcol];
        }
      }
}

// ---------------- per-row inverse L2 norm of bf16 matrix -------------------
__global__ __launch_bounds__(256) void norm_k(const u16* __restrict__ qb,
                                              float* __restrict__ inv, int rows, int dcols) {
  int gw = (int)((blockIdx.x * 256 + threadIdx.x) >> 6);
  int lane = threadIdx.x & 63;
  if (gw >= rows) return;
  const u16* r = qb + (size_t)gw * dcols;
  float s = 0.f;
  for (int c = lane; c < dcols; c += 64) { float v = b2f(r[c]); s += v * v; }
  for (int o = 32; o; o >>= 1) s += __shfl_down(s, o);
  if (lane == 0) inv[gw] = 1.f / fmaxf(sqrtf(s), 1e-12f);
}

// ===== per-row top-100 mean: lane-salted LDS histogram radix select ========
__global__ __launch_bounds__(256) void topk_k(const u16* __restrict__ Ablk,
                                              float* __restrict__ A1, int rowbase) {
  __shared__ u32 hist[16][257];
  __shared__ u32 histlo[8][257];
  __shared__ u32 chist[256];
  __shared__ u32 sfx[257];
  __shared__ float wsfx[257];
  __shared__ float wsum[4];
  __shared__ int s_bhi;
  __shared__ u32 s_above;
  __shared__ float s_tail;
  int row = blockIdx.x, tid = threadIdx.x, wid = tid >> 6, lane = tid & 63;
  const uint4* src4 = reinterpret_cast<const uint4*>(Ablk + (size_t)row * 16384);
  uint4 regs[8];
#pragma unroll
  for (int v = 0; v < 8; ++v) regs[v] = src4[v * 256 + tid];
  for (int i = tid; i < 16 * 257; i += 256) (&hist[0][0])[i] = 0;
  for (int i = tid; i < 8 * 257; i += 256) (&histlo[0][0])[i] = 0;
#pragma unroll
  for (int v = 0; v < 8; ++v) {
    u32* w = reinterpret_cast<u32*>(&regs[v]);
#pragma unroll
    for (int h = 0; h < 4; ++h) {
      u32 x = w[h];
      u16 lo = (u16)x, hi = (u16)(x >> 16);
      lo = (lo & 0x8000) ? (u16)(~lo) : (u16)(lo | 0x8000);
      hi = (hi & 0x8000) ? (u16)(~hi) : (u16)(hi | 0x8000);
      w[h] = (u32)lo | ((u32)hi << 16);
    }
  }
  __syncthreads();

  u32* myh = &hist[lane & 15][0];
#pragma unroll
  for (int v = 0; v < 8; ++v) {
    const u32* w = reinterpret_cast<const u32*>(&regs[v]);
#pragma unroll
    for (int h = 0; h < 4; ++h) {
      atomicAdd(&myh[(w[h] >> 8) & 0xffu], 1u);
      atomicAdd(&myh[w[h] >> 24], 1u);
    }
  }
  __syncthreads();
  {
    u32 c = 0;
#pragma unroll
    for (int j = 0; j < 16; ++j) c += hist[j][tid];
    sfx[tid] = c;
    if (tid == 0) sfx[256] = 0;
  }
  __syncthreads();
#pragma unroll
  for (int st = 1; st < 256; st <<= 1) {
    u32 add = (tid + st < 256) ? sfx[tid + st] : 0u;
    __syncthreads();
    sfx[tid] += add;
    __syncthreads();
  }
  if (sfx[tid] >= 100u && sfx[tid + 1] < 100u) {
    s_bhi = tid;
    s_above = sfx[tid + 1];
  }
  __syncthreads();
  u32 bhi = (u32)s_bhi, above = s_above;

  u32* myl = &histlo[lane & 7][0];
  float lsum = 0.f;
#pragma unroll
  for (int v = 0; v < 8; ++v) {
    const u32* w = reinterpret_cast<const u32*>(&regs[v]);
#pragma unroll
    for (int h = 0; h < 4; ++h) {
#pragma unroll
      for (int half = 0; half < 2; ++half) {
        u32 k = (w[h] >> (half * 16)) & 0xffffu;
        u32 hb = k >> 8;
        if (hb > bhi) lsum += key2f(k);
        else if (hb == bhi) atomicAdd(&myl[k & 0xffu], 1u);
      }
    }
  }
  for (int o = 32; o; o >>= 1) lsum += __shfl_down(lsum, o);
  if (lane == 0) wsum[wid] = lsum;
  __syncthreads();
  {
    u32 c = 0;
#pragma unroll
    for (int j = 0; j < 8; ++j) c += histlo[j][tid];
    chist[tid] = c;
    sfx[tid] = c;
    wsfx[tid] = (float)c * key2f((bhi << 8) | (u32)tid);
    if (tid == 0) { sfx[256] = 0; wsfx[256] = 0.f; }
  }
  __syncthreads();
#pragma unroll
  for (int st = 1; st < 256; st <<= 1) {
    u32 a = (tid + st < 256) ? sfx[tid + st] : 0u;
    float b = (tid + st < 256) ? wsfx[tid + st] : 0.f;
    __syncthreads();
    sfx[tid] += a;
    wsfx[tid] += b;
    __syncthreads();
  }
  {
    u32 need = 100u - above;
    if (sfx[tid] >= need && sfx[tid + 1] < need) {
      s_tail = wsfx[tid + 1] +
               (float)(need - sfx[tid + 1]) * key2f((bhi << 8) | (u32)tid);
    }
  }
  __syncthreads();
  if (tid == 0) {
    float tot = wsum[0] + wsum[1] + wsum[2] + wsum[3];
    A1[rowbase + row] = (tot + s_tail) * 0.01f;
  }
}

// ---------------- exact stable argsort: 2D partial counting rank -----------
__global__ __launch_bounds__(256) void rankpart_k(const float* __restrict__ A1,
                                                  u32* __restrict__ rank) {
  __shared__ u64 tile[2048];
  int i = blockIdx.x * 256 + threadIdx.x;
  int t0 = blockIdx.y * 2048;
  u64 my = makekey(A1[i], i);
  for (int j = threadIdx.x; j < 2048; j += 256) tile[j] = makekey(A1[t0 + j], t0 + j);
  __syncthreads();
  u32 r = 0;
  for (int j = 0; j < 2048; ++j) r += (tile[j] < my) ? 1u : 0u;
  atomicAdd(&rank[i], r);
}

__global__ __launch_bounds__(256) void scatter_k(const u32* __restrict__ rank,
                                                 u32* __restrict__ sortidx) {
  int i = blockIdx.x * 256 + threadIdx.x;
  sortidx[rank[i]] = (u32)i;
}

// ---------------- att logits z_i and g_i = feat_i . Wc ---------------------
__global__ __launch_bounds__(256) void attlogit_k(const float* __restrict__ avr,
                                                  const float* __restrict__ aur,
                                                  const float* __restrict__ featf,
                                                  const float* __restrict__ Wa,
                                                  const float* __restrict__ Wc,
                                                  float* __restrict__ z, float* __restrict__ g,
                                                  int M) {
  int gw = (int)((blockIdx.x * 256 + threadIdx.x) >> 6);
  int lane = threadIdx.x & 63;
  if (gw >= M) return;
  float s = 0.f;
  for (int c = lane; c < 256; c += 64) {
    float a = tanhf(avr[(size_t)gw * 256 + c]);
    float u = 1.f / (1.f + expf(-aur[(size_t)gw * 256 + c]));
    s += a * u * Wa[c];
  }
  float t = 0.f;
  for (int c = lane; c < 512; c += 64) t += featf[(size_t)gw * 512 + c] * Wc[c];
  for (int o = 32; o; o >>= 1) {
    s += __shfl_down(s, o);
    t += __shfl_down(t, o);
  }
  if (lane == 0) {
    z[gw] = s;
    g[gw] = t;
  }
}

// ---------------- softmax + outputs ----------------------------------------
__global__ __launch_bounds__(1024) void final_k(const float* __restrict__ z,
                                                const float* __restrict__ g,
                                                const float* __restrict__ bc,
                                                float* __restrict__ out, int M) {
  __shared__ float sred[16], s1[16], s2[16];
  int tid = threadIdx.x, lane = tid & 63, w = tid >> 6;
  float m = -1e30f;
  for (int i = tid; i < M; i += 1024) m = fmaxf(m, z[i]);
  for (int o = 32; o; o >>= 1) m = fmaxf(m, __shfl_down(m, o));
  if (lane == 0) sred[w] = m;
  __syncthreads();
  if (w == 0) {
    float t = (lane < 16) ? sred[lane] : -1e30f;
    for (int o = 8; o; o >>= 1) t = fmaxf(t, __shfl_down(t, o));
    if (lane == 0) sred[0] = t;
  }
  __syncthreads();
  m = sred[0];
  float se = 0.f, sg = 0.f;
  for (int i = tid; i < M; i += 1024) {
    float e = expf(z[i] - m);
    se += e;
    sg += e * g[i];
  }
  for (int o = 32; o; o >>= 1) {
    se += __shfl_down(se, o);
    sg += __shfl_down(sg, o);
  }
  if (lane == 0) {
    s1[w] = se;
    s2[w] = sg;
  }
  __syncthreads();
  if (w == 0) {
    float a = (lane < 16) ? s1[lane] : 0.f;
    float b = (lane < 16) ? s2[lane] : 0.f;
    for (int o = 8; o; o >>= 1) {
      a += __shfl_down(a, o);
      b += __shfl_down(b, o);
    }
    if (lane == 0) {
      s1[0] = a;
      s2[0] = b;
    }
  }
  __syncthreads();
  float inv = 1.f / s1[0];
  for (int i = tid; i < M; i += 1024) out[1 + i] = expf(z[i] - m) * inv;
  if (tid == 0) out[0] = s2[0] * inv + bc[0];
}

extern "C" void kernel_launch(void* const* d_in, const int* in_sizes, int n_in,
                              void* d_out, int out_size, void* d_ws, size_t ws_size,
                              hipStream_t stream) {
  const int N = 16384, D = 1024, HD = 512, HD2 = 256, MSEL = 4915;
  const float* x0 = (const float*)d_in[0];
  const float* x1 = (const float*)d_in[1];
  const float* Wq = (const float*)d_in[2];
  const float* bq = (const float*)d_in[3];
  const float* Wk = (const float*)d_in[4];
  const float* bk = (const float*)d_in[5];
  const float* W1 = (const float*)d_in[6];
  const float* b1 = (const float*)d_in[7];
  const float* Wv = (const float*)d_in[8];
  const float* bv = (const float*)d_in[9];
  const float* Wu = (const float*)d_in[10];
  const float* bu = (const float*)d_in[11];
  const float* Wa = (const float*)d_in[12];
  // d_in[13] = ba: softmax shift-invariant -> unused
  const float* Wc = (const float*)d_in[14];
  const float* bc = (const float*)d_in[15];
  float* out = (float*)d_out;

  char* base = (char*)d_ws;
  size_t off = 0;
  auto alloc = [&](size_t b) {
    void* r = base + off;
    off = (off + b + 255) & ~(size_t)255;
    return r;
  };
  const int MPAD = 4992;  // 39*128
  u16* wqt = (u16*)alloc((size_t)HD * D * 2);
  u16* wkt = (u16*)alloc((size_t)HD * D * 2);
  u16* w1t = (u16*)alloc((size_t)HD * D * 2);
  u16* wvt = (u16*)alloc((size_t)HD2 * HD * 2);
  u16* wut = (u16*)alloc((size_t)HD2 * HD * 2);
  u16* x0b = (u16*)alloc((size_t)N * D * 2);
  u16* x1b = (u16*)alloc((size_t)N * D * 2);
  u16* qb = (u16*)alloc((size_t)N * HD * 2);
  u16* kb = (u16*)alloc((size_t)N * HD * 2);
  float* invq = (float*)alloc((size_t)N * 4);
  float* invk = (float*)alloc((size_t)N * 4);
  float* A1 = (float*)alloc((size_t)N * 4);
  u32* rankbuf = (u32*)alloc((size_t)N * 4);
  u32* sortidx = (u32*)alloc((size_t)N * 4);
  float* featf = (float*)alloc((size_t)MPAD * HD * 4);
  u16* featb = (u16*)alloc((size_t)MPAD * HD * 2);
  float* avr = (float*)alloc((size_t)MPAD * HD2 * 4);
  float* aur = (float*)alloc((size_t)MPAD * HD2 * 4);
  float* zbuf = (float*)alloc((size_t)MPAD * 4);
  float* gbuf = (float*)alloc((size_t)MPAD * 4);
  const int ablk = 2048;
  u16* Ablk = (u16*)alloc((size_t)ablk * N * 2);

  // 1) convert inputs + weights to bf16
  conv_k<<<(N * D / 8 + 255) / 256, 256, 0, stream>>>(x0, x0b, N * D / 8);
  conv_k<<<(N * D / 8 + 255) / 256, 256, 0, stream>>>(x1, x1b, N * D / 8);
  convt_k<<<dim3(D / 32, HD / 32), 256, 0, stream>>>(Wq, wqt, D, HD);
  convt_k<<<dim3(D / 32, HD / 32), 256, 0, stream>>>(Wk, wkt, D, HD);
  convt_k<<<dim3(D / 32, HD / 32), 256, 0, stream>>>(W1, w1t, D, HD);
  convt_k<<<dim3(HD / 32, HD2 / 32), 256, 0, stream>>>(Wv, wvt, HD, HD2);
  convt_k<<<dim3(HD / 32, HD2 / 32), 256, 0, stream>>>(Wu, wut, HD, HD2);

  // 2) projections (8-phase 256^2): z=0 -> q = tanh(x0 Wq + bq), z=1 -> k
  mmT_k<0><<<dim3(2, 64, 2), 512, 0, stream>>>(
      x0b, wqt, D, 0, 64, nullptr, nullptr, bq, qb, HD,
      x1b, wkt, bk, kb);

  // 3) row inverse norms
  norm_k<<<N / 4, 256, 0, stream>>>(qb, invq, N, HD);
  norm_k<<<N / 4, 256, 0, stream>>>(kb, invk, N, HD);

  // 4) blocked score GEMM (8-phase 256^2) + per-row top-100 mean
  for (int it = 0; it < N / ablk; ++it) {
    mmT_k<1><<<dim3(8, 64), 512, 0, stream>>>(
        qb, kb, HD, it * ablk, 8, invq, invk, nullptr, Ablk, N,
        nullptr, nullptr, nullptr, nullptr);
    topk_k<<<ablk, 256, 0, stream>>>(Ablk, A1, it * ablk);
  }

  // 5) exact stable ascending argsort of A1 (partial ranks + scatter)
  hipMemsetAsync(rankbuf, 0, (size_t)N * 4, stream);
  rankpart_k<<<dim3(N / 256, 8), 256, 0, stream>>>(A1, rankbuf);
  scatter_k<<<N / 256, 256, 0, stream>>>(rankbuf, sortidx);

  // 6) feat = relu(x0[sel] W1 + b1)  (f32 + bf16 out)
  gemm2_k<2><<<dim3((MSEL + TILE - 1) / TILE, HD / TILE), 256, 0, stream>>>(
      x0b, w1t, D, D, D, MSEL, b1, sortidx, featf, featb, HD,
      nullptr, nullptr, nullptr, nullptr, nullptr);

  // 7) fused: z=0 -> av_raw = feat Wv + bv ; z=1 -> au_raw = feat Wu + bu
  gemm2_k<3><<<dim3((MSEL + TILE - 1) / TILE, HD2 / TILE, 2), 256, 0, stream>>>(
      featb, wvt, HD, HD, HD, MSEL, bv, nullptr, avr, nullptr, HD2,
      nullptr, wut, bu, aur, nullptr);

  // 8) logits + per-row feat.Wc
  attlogit_k<<<(MSEL + 3) / 4, 256, 0, stream>>>(avr, aur, featf, Wa, Wc, zbuf, gbuf, MSEL);

  // 9) softmax + outputs
  final_k<<<1, 1024, 0, stream>>>(zbuf, gbuf, bc, out, MSEL);
}

// Round 14
// 781.704 us; speedup vs baseline: 1.1862x; 1.1862x over previous
//
#include <hip/hip_runtime.h>

typedef unsigned short u16;
typedef unsigned int u32;
typedef unsigned long long u64;

typedef __attribute__((ext_vector_type(8))) short bf16x8;
typedef __attribute__((ext_vector_type(4))) float f32x4;

__device__ __forceinline__ u16 f2b(float f) {
  u32 u = __float_as_uint(f);
  u32 r = (u + 0x7fffu + ((u >> 16) & 1u)) >> 16;  // RNE
  return (u16)r;
}
__device__ __forceinline__ float b2f(u16 h) {
  return __uint_as_float(((u32)h) << 16);
}
__device__ __forceinline__ float key2f(u32 k) {
  u16 kk = (u16)k;
  u16 bits = (kk & 0x8000) ? (u16)(kk ^ 0x8000) : (u16)(~kk);
  return b2f(bits);
}
__device__ __forceinline__ u64 makekey(float f, int i) {
  u32 u = __float_as_uint(f);
  u = (u & 0x80000000u) ? ~u : (u | 0x80000000u);
  return ((u64)u << 32) | (u32)i;
}

__device__ __forceinline__ void gload16(const void* g, void* l) {
  __builtin_amdgcn_global_load_lds((const __attribute__((address_space(1))) void*)g,
                                   (__attribute__((address_space(3))) void*)l, 16, 0, 0);
}

// ---------------- fp32 -> bf16 convert (8 elems/thread) --------------------
__global__ __launch_bounds__(256) void conv_k(const float* __restrict__ s,
                                              u16* __restrict__ d, int n8) {
  int i = blockIdx.x * 256 + threadIdx.x;
  if (i >= n8) return;
  const float4* s4 = reinterpret_cast<const float4*>(s);
  float4 f0 = s4[i * 2], f1 = s4[i * 2 + 1];
  __align__(16) u16 t[8];
  t[0] = f2b(f0.x); t[1] = f2b(f0.y); t[2] = f2b(f0.z); t[3] = f2b(f0.w);
  t[4] = f2b(f1.x); t[5] = f2b(f1.y); t[6] = f2b(f1.z); t[7] = f2b(f1.w);
  reinterpret_cast<uint4*>(d)[i] = *reinterpret_cast<uint4*>(t);
}

// -------- transpose+convert W (K x Nc fp32) -> Wt (Nc x K bf16), LDS-tiled -
__global__ __launch_bounds__(256) void convt_k(const float* __restrict__ W,
                                               u16* __restrict__ Wt, int K, int Nc) {
  __shared__ float t[32][33];
  int k0 = blockIdx.x * 32, n0 = blockIdx.y * 32;
  int c = threadIdx.x & 31, r4 = threadIdx.x >> 5;
#pragma unroll
  for (int i = 0; i < 4; ++i) {
    int r = r4 + i * 8;
    t[r][c] = W[(size_t)(k0 + r) * Nc + n0 + c];  // coalesced on c
  }
  __syncthreads();
#pragma unroll
  for (int i = 0; i < 4; ++i) {
    int r = r4 + i * 8;
    Wt[(size_t)(n0 + r) * K + k0 + c] = f2b(t[c][r]);  // coalesced on c
  }
}

// ================ 4-phase 256x256 MFMA GEMM (score) ========================
// 8 waves (512 thr), BK=32, LDS 64KB. SINGLE barrier per phase; counted
// vmcnt placed AFTER the MFMA cluster (wait hides under compute). r11-best.
// MODE 1: score v*rs[row]*cs[col], bf16 out
template <int MODE>
__global__ __launch_bounds__(512, 2) void mm8_k(
    const u16* __restrict__ A, const u16* __restrict__ B, int K, int Mbase,
    int mtiles, const float* __restrict__ rs, const float* __restrict__ cs,
    const float* __restrict__ bias, u16* __restrict__ out, int ldc) {
  __shared__ u16 lds[2][2][2][128][32];  // [buf][mat][half][row][k]
  int tid = threadIdx.x, lane = tid & 63, wid = tid >> 6;
  int wm = wid >> 2, wn = wid & 3;
  int rsel = lane & 15, rgrp = lane >> 4;

  int nwg = gridDim.x * gridDim.y;
  int fid = blockIdx.y * gridDim.x + blockIdx.x;
  int chunk = nwg >> 3;
  int s = (fid & 7) * chunk + (fid >> 3);  // XCD-contiguous remap (nwg%8==0)
  int mtile = s % mtiles, ntile = s / mtiles;
  int mrow0 = Mbase + mtile * 256;
  int ncol0 = ntile * 256;

  int strow = wid * 16 + (lane >> 2);
  int stch = (lane & 3) ^ ((lane >> 3) & 3);  // pre-swizzled source chunk

  auto stage = [&](int sbuf, int smat, int shalf, int kt) {
    int grow = (smat ? ncol0 : mrow0) + shalf * 128 + strow;
    const u16* g = (smat ? B : A) + (size_t)grow * K + kt * 32 + stch * 8;
    gload16(g, &lds[sbuf][smat][shalf][wid * 16][0]);
  };

  f32x4 acc[4][4][2] = {};
  bf16x8 afr[4], bfr[2][2];

  auto rdA = [&](int buf, int ah) {
#pragma unroll
    for (int mf = 0; mf < 4; ++mf) {
      int row = wm * 64 + mf * 16 + rsel;
      afr[mf] = *reinterpret_cast<const bf16x8*>(
          &lds[buf][0][ah][row][(rgrp ^ ((row >> 1) & 3)) * 8]);
    }
  };
  auto rdB = [&](int buf) {
#pragma unroll
    for (int bh = 0; bh < 2; ++bh)
#pragma unroll
      for (int nf = 0; nf < 2; ++nf) {
        int row = wn * 32 + nf * 16 + rsel;
        bfr[bh][nf] = *reinterpret_cast<const bf16x8*>(
            &lds[buf][1][bh][row][(rgrp ^ ((row >> 1) & 3)) * 8]);
      }
  };
  auto mm = [&](int ah) {
#pragma unroll
    for (int bh = 0; bh < 2; ++bh)
#pragma unroll
      for (int mf = 0; mf < 4; ++mf)
#pragma unroll
        for (int nf = 0; nf < 2; ++nf)
          acc[ah * 2 + bh][mf][nf] = __builtin_amdgcn_mfma_f32_16x16x32_bf16(
              afr[mf], bfr[bh][nf], acc[ah * 2 + bh][mf][nf], 0, 0, 0);
  };

  int nkt = K / 32;
  stage(0, 0, 0, 0); stage(0, 1, 0, 0); stage(0, 1, 1, 0); stage(0, 0, 1, 0);
  stage(1, 0, 0, 1); stage(1, 1, 0, 1);
  asm volatile("s_waitcnt vmcnt(2)" ::: "memory");  // buf0 complete
  __builtin_amdgcn_s_barrier();

  for (int j = 0; j < nkt / 2; ++j) {
    int t1 = 2 * j + 1;
    int t2 = (2 * j + 2 < nkt) ? 2 * j + 2 : nkt - 1;  // clamped: never read
    int t3 = (2 * j + 3 < nkt) ? 2 * j + 3 : nkt - 1;
    // P0: compute buf0 half0; stage buf1.{B1,A1} <- t1
    rdB(0); rdA(0, 0);
    stage(1, 1, 1, t1); stage(1, 0, 1, t1);
    __builtin_amdgcn_s_setprio(1); mm(0); __builtin_amdgcn_s_setprio(0);
    __builtin_amdgcn_s_barrier();
    // P1: compute buf0 half1; stage buf0.{A0,B0} <- t2; late WAIT (buf1 ready)
    rdA(0, 1);
    stage(0, 0, 0, t2); stage(0, 1, 0, t2);
    __builtin_amdgcn_s_setprio(1); mm(1); __builtin_amdgcn_s_setprio(0);
    asm volatile("s_waitcnt vmcnt(2)" ::: "memory");
    __builtin_amdgcn_s_barrier();
    // P2: compute buf1 half0; stage buf0.{B1,A1} <- t2
    rdB(1); rdA(1, 0);
    stage(0, 1, 1, t2); stage(0, 0, 1, t2);
    __builtin_amdgcn_s_setprio(1); mm(0); __builtin_amdgcn_s_setprio(0);
    __builtin_amdgcn_s_barrier();
    // P3: compute buf1 half1; stage buf1.{A0,B0} <- t3; late WAIT (buf0 ready)
    rdA(1, 1);
    stage(1, 0, 0, t3); stage(1, 1, 0, t3);
    __builtin_amdgcn_s_setprio(1); mm(1); __builtin_amdgcn_s_setprio(0);
    asm volatile("s_waitcnt vmcnt(2)" ::: "memory");
    __builtin_amdgcn_s_barrier();
  }

#pragma unroll
  for (int q = 0; q < 4; ++q)
#pragma unroll
    for (int mf = 0; mf < 4; ++mf)
#pragma unroll
      for (int nf = 0; nf < 2; ++nf)
#pragma unroll
        for (int r = 0; r < 4; ++r) {
          int rl = mtile * 256 + (q >> 1) * 128 + wm * 64 + mf * 16 + rgrp * 4 + r;
          int cl = ncol0 + (q & 1) * 128 + wn * 32 + nf * 16 + rsel;
          float v = acc[q][mf][nf][r] * rs[Mbase + rl] * cs[cl];
          out[(size_t)rl * ldc + cl] = f2b(v);
        }
}

// ========== proj GEMM: 128x256 tile, 3-buffer, 16-MFMA phases ==============
// One phase per K-tile, SINGLE barrier: {8 ds_read | 3 gload(t+2) | 16 MFMA
// | vmcnt(3) | bar}. LDS 72KB -> 2 blocks/CU. z selects (x1,Wk). r11-best.
__global__ __launch_bounds__(512, 2) void mm8p_k(
    const u16* __restrict__ A, const u16* __restrict__ B, int K, int mtiles,
    const float* __restrict__ bias, u16* __restrict__ out, int ldc,
    const u16* A2, const u16* B2, const float* bias2, u16* out2) {
  if (blockIdx.z) { A = A2; B = B2; bias = bias2; out = out2; }
  __shared__ u16 lds[3][3][128][32];  // [buf][slot: A,B0,B1][row][k]
  int tid = threadIdx.x, lane = tid & 63, wid = tid >> 6;
  int wm = wid >> 2, wn = wid & 3;
  int rsel = lane & 15, rgrp = lane >> 4;

  int nwg = gridDim.x * gridDim.y;
  int fid = blockIdx.y * gridDim.x + blockIdx.x;
  int chunk = nwg >> 3;
  int s = (fid & 7) * chunk + (fid >> 3);
  int mtile = s % mtiles, ntile = s / mtiles;
  int mrow0 = mtile * 128;
  int ncol0 = ntile * 256;

  int strow = wid * 16 + (lane >> 2);
  int stch = (lane & 3) ^ ((lane >> 3) & 3);

  auto stage = [&](int sbuf, int slot, int kt) {
    int grow = (slot == 0 ? mrow0 : ncol0 + (slot - 1) * 128) + strow;
    const u16* g = (slot == 0 ? A : B) + (size_t)grow * K + kt * 32 + stch * 8;
    gload16(g, &lds[sbuf][slot][wid * 16][0]);
  };

  f32x4 acc[2][4][2] = {};
  bf16x8 afr[4], bfr[2][2];

  auto rdAll = [&](int buf) {
#pragma unroll
    for (int mf = 0; mf < 4; ++mf) {
      int row = wm * 64 + mf * 16 + rsel;
      afr[mf] = *reinterpret_cast<const bf16x8*>(
          &lds[buf][0][row][(rgrp ^ ((row >> 1) & 3)) * 8]);
    }
#pragma unroll
    for (int bh = 0; bh < 2; ++bh)
#pragma unroll
      for (int nf = 0; nf < 2; ++nf) {
        int row = wn * 32 + nf * 16 + rsel;
        bfr[bh][nf] = *reinterpret_cast<const bf16x8*>(
            &lds[buf][1 + bh][row][(rgrp ^ ((row >> 1) & 3)) * 8]);
      }
  };
  auto mm16 = [&]() {
#pragma unroll
    for (int bh = 0; bh < 2; ++bh)
#pragma unroll
      for (int mf = 0; mf < 4; ++mf)
#pragma unroll
        for (int nf = 0; nf < 2; ++nf)
          acc[bh][mf][nf] = __builtin_amdgcn_mfma_f32_16x16x32_bf16(
              afr[mf], bfr[bh][nf], acc[bh][mf][nf], 0, 0, 0);
  };

  int nkt = K / 32;
  stage(0, 0, 0); stage(0, 1, 0); stage(0, 2, 0);
  stage(1, 0, 1); stage(1, 1, 1); stage(1, 2, 1);
  asm volatile("s_waitcnt vmcnt(3)" ::: "memory");  // t0 landed
  __builtin_amdgcn_s_barrier();

  int cur = 0;
  for (int t = 0; t < nkt; ++t) {
    rdAll(cur);
    int tn = (t + 2 < nkt) ? t + 2 : nkt - 1;  // clamped junk: never read
    int nb = cur + 2; if (nb >= 3) nb -= 3;
    stage(nb, 0, tn); stage(nb, 1, tn); stage(nb, 2, tn);
    __builtin_amdgcn_s_setprio(1); mm16(); __builtin_amdgcn_s_setprio(0);
    asm volatile("s_waitcnt vmcnt(3)" ::: "memory");  // tile t+1 landed
    __builtin_amdgcn_s_barrier();
    cur = (cur + 1 == 3) ? 0 : cur + 1;
  }

#pragma unroll
  for (int bh = 0; bh < 2; ++bh)
#pragma unroll
    for (int mf = 0; mf < 4; ++mf)
#pragma unroll
      for (int nf = 0; nf < 2; ++nf)
#pragma unroll
        for (int r = 0; r < 4; ++r) {
          int rl = mrow0 + wm * 64 + mf * 16 + rgrp * 4 + r;
          int cl = ncol0 + bh * 128 + wn * 32 + nf * 16 + rsel;
          float v = tanhf(acc[bh][mf][nf][r] + bias[cl]);
          out[(size_t)rl * ldc + cl] = f2b(v);
        }
}

// ---------------- unified bf16 MFMA GEMM: C = A * B^T ----------------------
// 2-phase dbuf. MODE 2: feat (gather, bias+relu, f32+bf16). MODE 3: vu.
#define TILE 128
#define BK 32

template <int MODE>
__global__ __launch_bounds__(256) void gemm2_k(
    const u16* __restrict__ Abf, const u16* __restrict__ Bbf, int lda, int ldb,
    int K, int Mreal, const float* __restrict__ bias,
    const u32* __restrict__ gidx, float* __restrict__ outf,
    u16* __restrict__ outb, int ldc,
    const u16* Abf2, const u16* Bbf2, const float* bias2,
    float* outf2, u16* outb2) {
  if (blockIdx.z) {
    if (Abf2) Abf = Abf2;
    if (Bbf2) Bbf = Bbf2;
    if (bias2) bias = bias2;
    if (outf2) outf = outf2;
    if (outb2) outb = outb2;
  }
  __shared__ u16 As[2][TILE][BK];
  __shared__ u16 Bs[2][TILE][BK];
  int tid = threadIdx.x, lane = tid & 63, wid = tid >> 6;
  int mt = blockIdx.x, nt2 = blockIdx.y;
  int row0 = (wid >> 1) * 64, col0 = (wid & 1) * 64;

  int scol = (lane & 3) * 8;
  const u16* gA[2];
  const u16* gB[2];
#pragma unroll
  for (int h = 0; h < 2; ++h) {
    int rA = (wid * 2 + h) * 16 + (lane >> 2);
    int grow = mt * TILE + rA;
    int arow;
    if (MODE == 2) arow = (int)gidx[grow < Mreal ? grow : 0];
    else arow = grow;
    gA[h] = Abf + (size_t)arow * lda + scol;
    int bcol = nt2 * TILE + rA;
    gB[h] = Bbf + (size_t)bcol * ldb + scol;
  }

  auto stage = [&](int buf, int kt) {
#pragma unroll
    for (int h = 0; h < 2; ++h) {
      gload16(gA[h] + kt, &As[buf][(wid * 2 + h) * 16][0]);
      gload16(gB[h] + kt, &Bs[buf][(wid * 2 + h) * 16][0]);
    }
  };

  f32x4 acc[4][4] = {};
  int k8 = 8 * (lane >> 4), rsel = lane & 15;
  int nkt = K / BK;

  stage(0, 0);
  __syncthreads();
  int cur = 0;
  for (int t = 0; t < nkt; ++t) {
    if (t + 1 < nkt) stage(cur ^ 1, (t + 1) * BK);
    bf16x8 a[4], b[4];
#pragma unroll
    for (int m = 0; m < 4; ++m)
      a[m] = *reinterpret_cast<const bf16x8*>(&As[cur][row0 + m * 16 + rsel][k8]);
#pragma unroll
    for (int n = 0; n < 4; ++n)
      b[n] = *reinterpret_cast<const bf16x8*>(&Bs[cur][col0 + n * 16 + rsel][k8]);
    __builtin_amdgcn_s_setprio(1);
#pragma unroll
    for (int m = 0; m < 4; ++m)
#pragma unroll
      for (int n = 0; n < 4; ++n)
        acc[m][n] = __builtin_amdgcn_mfma_f32_16x16x32_bf16(a[m], b[n], acc[m][n], 0, 0, 0);
    __builtin_amdgcn_s_setprio(0);
    __syncthreads();
    cur ^= 1;
  }

  int rgrp = lane >> 4, csel = lane & 15;
#pragma unroll
  for (int m = 0; m < 4; ++m)
#pragma unroll
    for (int n = 0; n < 4; ++n)
#pragma unroll
      for (int r = 0; r < 4; ++r) {
        int grow = mt * TILE + row0 + m * 16 + rgrp * 4 + r;
        int gcol = nt2 * TILE + col0 + n * 16 + csel;
        float v = acc[m][n][r];
        if (MODE == 2) {
          if (grow < Mreal) {
            v = fmaxf(v + bias[gcol], 0.f);
            outf[(size_t)grow * ldc + gcol] = v;
            outb[(size_t)grow * ldc + gcol] = f2b(v);
          }
        } else {
          if (grow < Mreal) outf[(size_t)grow * ldc + gcol] = v + bias[gcol];
        }
      }
}

// ---------------- per-row inverse L2 norm of bf16 matrix -------------------
__global__ __launch_bounds__(256) void norm_k(const u16* __restrict__ qb,
                                              float* __restrict__ inv, int rows, int dcols) {
  int gw = (int)((blockIdx.x * 256 + threadIdx.x) >> 6);
  int lane = threadIdx.x & 63;
  if (gw >= rows) return;
  const u16* r = qb + (size_t)gw * dcols;
  float s = 0.f;
  for (int c = lane; c < dcols; c += 64) { float v = b2f(r[c]); s += v * v; }
  for (int o = 32; o; o >>= 1) s += __shfl_down(s, o);
  if (lane == 0) inv[gw] = 1.f / fmaxf(sqrtf(s), 1e-12f);
}

// ===== per-row top-100 mean: lane-salted LDS histogram radix select ========
__global__ __launch_bounds__(256) void topk_k(const u16* __restrict__ Ablk,
                                              float* __restrict__ A1, int rowbase) {
  __shared__ u32 hist[16][257];
  __shared__ u32 histlo[8][257];
  __shared__ u32 chist[256];
  __shared__ u32 sfx[257];
  __shared__ float wsfx[257];
  __shared__ float wsum[4];
  __shared__ int s_bhi;
  __shared__ u32 s_above;
  __shared__ float s_tail;
  int row = blockIdx.x, tid = threadIdx.x, wid = tid >> 6, lane = tid & 63;
  const uint4* src4 = reinterpret_cast<const uint4*>(Ablk + (size_t)row * 16384);
  uint4 regs[8];
#pragma unroll
  for (int v = 0; v < 8; ++v) regs[v] = src4[v * 256 + tid];
  for (int i = tid; i < 16 * 257; i += 256) (&hist[0][0])[i] = 0;
  for (int i = tid; i < 8 * 257; i += 256) (&histlo[0][0])[i] = 0;
#pragma unroll
  for (int v = 0; v < 8; ++v) {
    u32* w = reinterpret_cast<u32*>(&regs[v]);
#pragma unroll
    for (int h = 0; h < 4; ++h) {
      u32 x = w[h];
      u16 lo = (u16)x, hi = (u16)(x >> 16);
      lo = (lo & 0x8000) ? (u16)(~lo) : (u16)(lo | 0x8000);
      hi = (hi & 0x8000) ? (u16)(~hi) : (u16)(hi | 0x8000);
      w[h] = (u32)lo | ((u32)hi << 16);
    }
  }
  __syncthreads();

  u32* myh = &hist[lane & 15][0];
#pragma unroll
  for (int v = 0; v < 8; ++v) {
    const u32* w = reinterpret_cast<const u32*>(&regs[v]);
#pragma unroll
    for (int h = 0; h < 4; ++h) {
      atomicAdd(&myh[(w[h] >> 8) & 0xffu], 1u);
      atomicAdd(&myh[w[h] >> 24], 1u);
    }
  }
  __syncthreads();
  {
    u32 c = 0;
#pragma unroll
    for (int j = 0; j < 16; ++j) c += hist[j][tid];
    sfx[tid] = c;
    if (tid == 0) sfx[256] = 0;
  }
  __syncthreads();
#pragma unroll
  for (int st = 1; st < 256; st <<= 1) {
    u32 add = (tid + st < 256) ? sfx[tid + st] : 0u;
    __syncthreads();
    sfx[tid] += add;
    __syncthreads();
  }
  if (sfx[tid] >= 100u && sfx[tid + 1] < 100u) {
    s_bhi = tid;
    s_above = sfx[tid + 1];
  }
  __syncthreads();
  u32 bhi = (u32)s_bhi, above = s_above;

  u32* myl = &histlo[lane & 7][0];
  float lsum = 0.f;
#pragma unroll
  for (int v = 0; v < 8; ++v) {
    const u32* w = reinterpret_cast<const u32*>(&regs[v]);
#pragma unroll
    for (int h = 0; h < 4; ++h) {
#pragma unroll
      for (int half = 0; half < 2; ++half) {
        u32 k = (w[h] >> (half * 16)) & 0xffffu;
        u32 hb = k >> 8;
        if (hb > bhi) lsum += key2f(k);
        else if (hb == bhi) atomicAdd(&myl[k & 0xffu], 1u);
      }
    }
  }
  for (int o = 32; o; o >>= 1) lsum += __shfl_down(lsum, o);
  if (lane == 0) wsum[wid] = lsum;
  __syncthreads();
  {
    u32 c = 0;
#pragma unroll
    for (int j = 0; j < 8; ++j) c += histlo[j][tid];
    chist[tid] = c;
    sfx[tid] = c;
    wsfx[tid] = (float)c * key2f((bhi << 8) | (u32)tid);
    if (tid == 0) { sfx[256] = 0; wsfx[256] = 0.f; }
  }
  __syncthreads();
#pragma unroll
  for (int st = 1; st < 256; st <<= 1) {
    u32 a = (tid + st < 256) ? sfx[tid + st] : 0u;
    float b = (tid + st < 256) ? wsfx[tid + st] : 0.f;
    __syncthreads();
    sfx[tid] += a;
    wsfx[tid] += b;
    __syncthreads();
  }
  {
    u32 need = 100u - above;
    if (sfx[tid] >= need && sfx[tid + 1] < need) {
      s_tail = wsfx[tid + 1] +
               (float)(need - sfx[tid + 1]) * key2f((bhi << 8) | (u32)tid);
    }
  }
  __syncthreads();
  if (tid == 0) {
    float tot = wsum[0] + wsum[1] + wsum[2] + wsum[3];
    A1[rowbase + row] = (tot + s_tail) * 0.01f;
  }
}

// ---------------- exact stable argsort: 2D partial counting rank -----------
__global__ __launch_bounds__(256) void rankpart_k(const float* __restrict__ A1,
                                                  u32* __restrict__ rank) {
  __shared__ u64 tile[2048];
  int i = blockIdx.x * 256 + threadIdx.x;
  int t0 = blockIdx.y * 2048;
  u64 my = makekey(A1[i], i);
  for (int j = threadIdx.x; j < 2048; j += 256) tile[j] = makekey(A1[t0 + j], t0 + j);
  __syncthreads();
  u32 r = 0;
  for (int j = 0; j < 2048; ++j) r += (tile[j] < my) ? 1u : 0u;
  atomicAdd(&rank[i], r);
}

__global__ __launch_bounds__(256) void scatter_k(const u32* __restrict__ rank,
                                                 u32* __restrict__ sortidx) {
  int i = blockIdx.x * 256 + threadIdx.x;
  sortidx[rank[i]] = (u32)i;
}

// ---------------- att logits z_i and g_i = feat_i . Wc ---------------------
__global__ __launch_bounds__(256) void attlogit_k(const float* __restrict__ avr,
                                                  const float* __restrict__ aur,
                                                  const float* __restrict__ featf,
                                                  const float* __restrict__ Wa,
                                                  const float* __restrict__ Wc,
                                                  float* __restrict__ z, float* __restrict__ g,
                                                  int M) {
  int gw = (int)((blockIdx.x * 256 + threadIdx.x) >> 6);
  int lane = threadIdx.x & 63;
  if (gw >= M) return;
  float s = 0.f;
  for (int c = lane; c < 256; c += 64) {
    float a = tanhf(avr[(size_t)gw * 256 + c]);
    float u = 1.f / (1.f + expf(-aur[(size_t)gw * 256 + c]));
    s += a * u * Wa[c];
  }
  float t = 0.f;
  for (int c = lane; c < 512; c += 64) t += featf[(size_t)gw * 512 + c] * Wc[c];
  for (int o = 32; o; o >>= 1) {
    s += __shfl_down(s, o);
    t += __shfl_down(t, o);
  }
  if (lane == 0) {
    z[gw] = s;
    g[gw] = t;
  }
}

// ---------------- softmax + outputs ----------------------------------------
__global__ __launch_bounds__(1024) void final_k(const float* __restrict__ z,
                                                const float* __restrict__ g,
                                                const float* __restrict__ bc,
                                                float* __restrict__ out, int M) {
  __shared__ float sred[16], s1[16], s2[16];
  int tid = threadIdx.x, lane = tid & 63, w = tid >> 6;
  float m = -1e30f;
  for (int i = tid; i < M; i += 1024) m = fmaxf(m, z[i]);
  for (int o = 32; o; o >>= 1) m = fmaxf(m, __shfl_down(m, o));
  if (lane == 0) sred[w] = m;
  __syncthreads();
  if (w == 0) {
    float t = (lane < 16) ? sred[lane] : -1e30f;
    for (int o = 8; o; o >>= 1) t = fmaxf(t, __shfl_down(t, o));
    if (lane == 0) sred[0] = t;
  }
  __syncthreads();
  m = sred[0];
  float se = 0.f, sg = 0.f;
  for (int i = tid; i < M; i += 1024) {
    float e = expf(z[i] - m);
    se += e;
    sg += e * g[i];
  }
  for (int o = 32; o; o >>= 1) {
    se += __shfl_down(se, o);
    sg += __shfl_down(sg, o);
  }
  if (lane == 0) {
    s1[w] = se;
    s2[w] = sg;
  }
  __syncthreads();
  if (w == 0) {
    float a = (lane < 16) ? s1[lane] : 0.f;
    float b = (lane < 16) ? s2[lane] : 0.f;
    for (int o = 8; o; o >>= 1) {
      a += __shfl_down(a, o);
      b += __shfl_down(b, o);
    }
    if (lane == 0) {
      s1[0] = a;
      s2[0] = b;
    }
  }
  __syncthreads();
  float inv = 1.f / s1[0];
  for (int i = tid; i < M; i += 1024) out[1 + i] = expf(z[i] - m) * inv;
  if (tid == 0) out[0] = s2[0] * inv + bc[0];
}

extern "C" void kernel_launch(void* const* d_in, const int* in_sizes, int n_in,
                              void* d_out, int out_size, void* d_ws, size_t ws_size,
                              hipStream_t stream) {
  const int N = 16384, D = 1024, HD = 512, HD2 = 256, MSEL = 4915;
  const float* x0 = (const float*)d_in[0];
  const float* x1 = (const float*)d_in[1];
  const float* Wq = (const float*)d_in[2];
  const float* bq = (const float*)d_in[3];
  const float* Wk = (const float*)d_in[4];
  const float* bk = (const float*)d_in[5];
  const float* W1 = (const float*)d_in[6];
  const float* b1 = (const float*)d_in[7];
  const float* Wv = (const float*)d_in[8];
  const float* bv = (const float*)d_in[9];
  const float* Wu = (const float*)d_in[10];
  const float* bu = (const float*)d_in[11];
  const float* Wa = (const float*)d_in[12];
  // d_in[13] = ba: softmax shift-invariant -> unused
  const float* Wc = (const float*)d_in[14];
  const float* bc = (const float*)d_in[15];
  float* out = (float*)d_out;

  char* base = (char*)d_ws;
  size_t off = 0;
  auto alloc = [&](size_t b) {
    void* r = base + off;
    off = (off + b + 255) & ~(size_t)255;
    return r;
  };
  const int MPAD = 4992;  // 39*128
  u16* wqt = (u16*)alloc((size_t)HD * D * 2);
  u16* wkt = (u16*)alloc((size_t)HD * D * 2);
  u16* w1t = (u16*)alloc((size_t)HD * D * 2);
  u16* wvt = (u16*)alloc((size_t)HD2 * HD * 2);
  u16* wut = (u16*)alloc((size_t)HD2 * HD * 2);
  u16* x0b = (u16*)alloc((size_t)N * D * 2);
  u16* x1b = (u16*)alloc((size_t)N * D * 2);
  u16* qb = (u16*)alloc((size_t)N * HD * 2);
  u16* kb = (u16*)alloc((size_t)N * HD * 2);
  float* invq = (float*)alloc((size_t)N * 4);
  float* invk = (float*)alloc((size_t)N * 4);
  float* A1 = (float*)alloc((size_t)N * 4);
  u32* rankbuf = (u32*)alloc((size_t)N * 4);
  u32* sortidx = (u32*)alloc((size_t)N * 4);
  float* featf = (float*)alloc((size_t)MPAD * HD * 4);
  u16* featb = (u16*)alloc((size_t)MPAD * HD * 2);
  float* avr = (float*)alloc((size_t)MPAD * HD2 * 4);
  float* aur = (float*)alloc((size_t)MPAD * HD2 * 4);
  float* zbuf = (float*)alloc((size_t)MPAD * 4);
  float* gbuf = (float*)alloc((size_t)MPAD * 4);
  // score slab: prefer 4096 rows (halves launch boundaries); shrink if ws short
  int ablk = 4096;
  while (ablk > 256 && off + (size_t)ablk * N * 2 > ws_size) ablk >>= 1;
  u16* Ablk = (u16*)alloc((size_t)ablk * N * 2);

  // 1) convert inputs + weights to bf16 (LDS-tiled transpose for weights)
  conv_k<<<(N * D / 8 + 255) / 256, 256, 0, stream>>>(x0, x0b, N * D / 8);
  conv_k<<<(N * D / 8 + 255) / 256, 256, 0, stream>>>(x1, x1b, N * D / 8);
  convt_k<<<dim3(D / 32, HD / 32), 256, 0, stream>>>(Wq, wqt, D, HD);
  convt_k<<<dim3(D / 32, HD / 32), 256, 0, stream>>>(Wk, wkt, D, HD);
  convt_k<<<dim3(D / 32, HD / 32), 256, 0, stream>>>(W1, w1t, D, HD);
  convt_k<<<dim3(HD / 32, HD2 / 32), 256, 0, stream>>>(Wv, wvt, HD, HD2);
  convt_k<<<dim3(HD / 32, HD2 / 32), 256, 0, stream>>>(Wu, wut, HD, HD2);

  // 2) projections fused (3-buffer 128x256, 512 blocks): z=0 -> q, z=1 -> k
  mm8p_k<<<dim3(4, 64, 2), 512, 0, stream>>>(
      x0b, wqt, D, 128, bq, qb, HD, x1b, wkt, bk, kb);

  // 3) row inverse norms
  norm_k<<<N / 4, 256, 0, stream>>>(qb, invq, N, HD);
  norm_k<<<N / 4, 256, 0, stream>>>(kb, invk, N, HD);

  // 4) blocked score GEMM (4-phase 256^2) + per-row top-100 mean
  for (int it = 0; it < N / ablk; ++it) {
    mm8_k<1><<<dim3(ablk / 256, 64), 512, 0, stream>>>(
        qb, kb, HD, it * ablk, ablk / 256, invq, invk, nullptr, Ablk, N);
    topk_k<<<ablk, 256, 0, stream>>>(Ablk, A1, it * ablk);
  }

  // 5) exact stable ascending argsort of A1 (partial ranks + scatter)
  hipMemsetAsync(rankbuf, 0, (size_t)N * 4, stream);
  rankpart_k<<<dim3(N / 256, 8), 256, 0, stream>>>(A1, rankbuf);
  scatter_k<<<N / 256, 256, 0, stream>>>(rankbuf, sortidx);

  // 6) feat = relu(x0[sel] W1 + b1)  (f32 + bf16 out)
  gemm2_k<2><<<dim3((MSEL + TILE - 1) / TILE, HD / TILE), 256, 0, stream>>>(
      x0b, w1t, D, D, D, MSEL, b1, sortidx, featf, featb, HD,
      nullptr, nullptr, nullptr, nullptr, nullptr);

  // 7) fused: z=0 -> av_raw = feat Wv + bv ; z=1 -> au_raw = feat Wu + bu
  gemm2_k<3><<<dim3((MSEL + TILE - 1) / TILE, HD2 / TILE, 2), 256, 0, stream>>>(
      featb, wvt, HD, HD, HD, MSEL, bv, nullptr, avr, nullptr, HD2,
      nullptr, wut, bu, aur, nullptr);

  // 8) logits + per-row feat.Wc
  attlogit_k<<<(MSEL + 3) / 4, 256, 0, stream>>>(avr, aur, featf, Wa, Wc, zbuf, gbuf, MSEL);

  // 9) softmax + outputs
  final_k<<<1, 1024, 0, stream>>>(zbuf, gbuf, bc, out, MSEL);
}

// Round 15
// 693.967 us; speedup vs baseline: 1.3361x; 1.1264x over previous
//
#include <hip/hip_runtime.h>

typedef unsigned short u16;
typedef unsigned int u32;
typedef unsigned long long u64;

typedef __attribute__((ext_vector_type(8))) short bf16x8;
typedef __attribute__((ext_vector_type(4))) float f32x4;

__device__ __forceinline__ u16 f2b(float f) {
  u32 u = __float_as_uint(f);
  u32 r = (u + 0x7fffu + ((u >> 16) & 1u)) >> 16;  // RNE
  return (u16)r;
}
__device__ __forceinline__ float b2f(u16 h) {
  return __uint_as_float(((u32)h) << 16);
}
__device__ __forceinline__ float key2f(u32 k) {
  u16 kk = (u16)k;
  u16 bits = (kk & 0x8000) ? (u16)(kk ^ 0x8000) : (u16)(~kk);
  return b2f(bits);
}
__device__ __forceinline__ u64 makekey(float f, int i) {
  u32 u = __float_as_uint(f);
  u = (u & 0x80000000u) ? ~u : (u | 0x80000000u);
  return ((u64)u << 32) | (u32)i;
}

__device__ __forceinline__ void gload16(const void* g, void* l) {
  __builtin_amdgcn_global_load_lds((const __attribute__((address_space(1))) void*)g,
                                   (__attribute__((address_space(3))) void*)l, 16, 0, 0);
}

// ------- fp32 -> bf16 convert (8 elems/thread); y selects (src,dst) --------
__global__ __launch_bounds__(256) void conv_k(const float* __restrict__ s0,
                                              u16* __restrict__ d0,
                                              const float* __restrict__ s1,
                                              u16* __restrict__ d1, int n8) {
  const float* s = blockIdx.y ? s1 : s0;
  u16* d = blockIdx.y ? d1 : d0;
  int i = blockIdx.x * 256 + threadIdx.x;
  if (i >= n8) return;
  const float4* s4 = reinterpret_cast<const float4*>(s);
  float4 f0 = s4[i * 2], f1 = s4[i * 2 + 1];
  __align__(16) u16 t[8];
  t[0] = f2b(f0.x); t[1] = f2b(f0.y); t[2] = f2b(f0.z); t[3] = f2b(f0.w);
  t[4] = f2b(f1.x); t[5] = f2b(f1.y); t[6] = f2b(f1.z); t[7] = f2b(f1.w);
  reinterpret_cast<uint4*>(d)[i] = *reinterpret_cast<uint4*>(t);
}

// -------- transpose+convert W (K x Nc fp32) -> Wt (Nc x K bf16), LDS-tiled -
__global__ __launch_bounds__(256) void convt_k(const float* __restrict__ W,
                                               u16* __restrict__ Wt, int K, int Nc) {
  __shared__ float t[32][33];
  int k0 = blockIdx.x * 32, n0 = blockIdx.y * 32;
  int c = threadIdx.x & 31, r4 = threadIdx.x >> 5;
#pragma unroll
  for (int i = 0; i < 4; ++i) {
    int r = r4 + i * 8;
    t[r][c] = W[(size_t)(k0 + r) * Nc + n0 + c];  // coalesced on c
  }
  __syncthreads();
#pragma unroll
  for (int i = 0; i < 4; ++i) {
    int r = r4 + i * 8;
    Wt[(size_t)(n0 + r) * K + k0 + c] = f2b(t[c][r]);  // coalesced on c
  }
}

// ================ 4-phase 256x256 MFMA GEMM (score) ========================
// 8 waves (512 thr), BK=32, LDS 64KB. SINGLE barrier per phase; counted
// vmcnt placed AFTER the MFMA cluster. r11/r14-best structure.
// MODE 1: score v*rs[row]*cs[col], bf16 out
template <int MODE>
__global__ __launch_bounds__(512, 2) void mm8_k(
    const u16* __restrict__ A, const u16* __restrict__ B, int K, int Mbase,
    int mtiles, const float* __restrict__ rs, const float* __restrict__ cs,
    const float* __restrict__ bias, u16* __restrict__ out, int ldc) {
  __shared__ u16 lds[2][2][2][128][32];  // [buf][mat][half][row][k]
  int tid = threadIdx.x, lane = tid & 63, wid = tid >> 6;
  int wm = wid >> 2, wn = wid & 3;
  int rsel = lane & 15, rgrp = lane >> 4;

  int nwg = gridDim.x * gridDim.y;
  int fid = blockIdx.y * gridDim.x + blockIdx.x;
  int chunk = nwg >> 3;
  int s = (fid & 7) * chunk + (fid >> 3);  // XCD-contiguous remap (nwg%8==0)
  int mtile = s % mtiles, ntile = s / mtiles;
  int mrow0 = Mbase + mtile * 256;
  int ncol0 = ntile * 256;

  int strow = wid * 16 + (lane >> 2);
  int stch = (lane & 3) ^ ((lane >> 3) & 3);  // pre-swizzled source chunk

  auto stage = [&](int sbuf, int smat, int shalf, int kt) {
    int grow = (smat ? ncol0 : mrow0) + shalf * 128 + strow;
    const u16* g = (smat ? B : A) + (size_t)grow * K + kt * 32 + stch * 8;
    gload16(g, &lds[sbuf][smat][shalf][wid * 16][0]);
  };

  f32x4 acc[4][4][2] = {};
  bf16x8 afr[4], bfr[2][2];

  auto rdA = [&](int buf, int ah) {
#pragma unroll
    for (int mf = 0; mf < 4; ++mf) {
      int row = wm * 64 + mf * 16 + rsel;
      afr[mf] = *reinterpret_cast<const bf16x8*>(
          &lds[buf][0][ah][row][(rgrp ^ ((row >> 1) & 3)) * 8]);
    }
  };
  auto rdB = [&](int buf) {
#pragma unroll
    for (int bh = 0; bh < 2; ++bh)
#pragma unroll
      for (int nf = 0; nf < 2; ++nf) {
        int row = wn * 32 + nf * 16 + rsel;
        bfr[bh][nf] = *reinterpret_cast<const bf16x8*>(
            &lds[buf][1][bh][row][(rgrp ^ ((row >> 1) & 3)) * 8]);
      }
  };
  auto mm = [&](int ah) {
#pragma unroll
    for (int bh = 0; bh < 2; ++bh)
#pragma unroll
      for (int mf = 0; mf < 4; ++mf)
#pragma unroll
        for (int nf = 0; nf < 2; ++nf)
          acc[ah * 2 + bh][mf][nf] = __builtin_amdgcn_mfma_f32_16x16x32_bf16(
              afr[mf], bfr[bh][nf], acc[ah * 2 + bh][mf][nf], 0, 0, 0);
  };

  int nkt = K / 32;
  stage(0, 0, 0, 0); stage(0, 1, 0, 0); stage(0, 1, 1, 0); stage(0, 0, 1, 0);
  stage(1, 0, 0, 1); stage(1, 1, 0, 1);
  asm volatile("s_waitcnt vmcnt(2)" ::: "memory");  // buf0 complete
  __builtin_amdgcn_s_barrier();

  for (int j = 0; j < nkt / 2; ++j) {
    int t1 = 2 * j + 1;
    int t2 = (2 * j + 2 < nkt) ? 2 * j + 2 : nkt - 1;  // clamped: never read
    int t3 = (2 * j + 3 < nkt) ? 2 * j + 3 : nkt - 1;
    rdB(0); rdA(0, 0);
    stage(1, 1, 1, t1); stage(1, 0, 1, t1);
    __builtin_amdgcn_s_setprio(1); mm(0); __builtin_amdgcn_s_setprio(0);
    __builtin_amdgcn_s_barrier();
    rdA(0, 1);
    stage(0, 0, 0, t2); stage(0, 1, 0, t2);
    __builtin_amdgcn_s_setprio(1); mm(1); __builtin_amdgcn_s_setprio(0);
    asm volatile("s_waitcnt vmcnt(2)" ::: "memory");
    __builtin_amdgcn_s_barrier();
    rdB(1); rdA(1, 0);
    stage(0, 1, 1, t2); stage(0, 0, 1, t2);
    __builtin_amdgcn_s_setprio(1); mm(0); __builtin_amdgcn_s_setprio(0);
    __builtin_amdgcn_s_barrier();
    rdA(1, 1);
    stage(1, 0, 0, t3); stage(1, 1, 0, t3);
    __builtin_amdgcn_s_setprio(1); mm(1); __builtin_amdgcn_s_setprio(0);
    asm volatile("s_waitcnt vmcnt(2)" ::: "memory");
    __builtin_amdgcn_s_barrier();
  }

#pragma unroll
  for (int q = 0; q < 4; ++q)
#pragma unroll
    for (int mf = 0; mf < 4; ++mf)
#pragma unroll
      for (int nf = 0; nf < 2; ++nf)
#pragma unroll
        for (int r = 0; r < 4; ++r) {
          int rl = mtile * 256 + (q >> 1) * 128 + wm * 64 + mf * 16 + rgrp * 4 + r;
          int cl = ncol0 + (q & 1) * 128 + wn * 32 + nf * 16 + rsel;
          float v = acc[q][mf][nf][r] * rs[Mbase + rl] * cs[cl];
          out[(size_t)rl * ldc + cl] = f2b(v);
        }
}

// ========== proj GEMM: 128x256 tile, 3-buffer, 16-MFMA phases ==============
// One phase per K-tile, SINGLE barrier. LDS 72KB -> 2 blocks/CU. r11-best.
__global__ __launch_bounds__(512, 2) void mm8p_k(
    const u16* __restrict__ A, const u16* __restrict__ B, int K, int mtiles,
    const float* __restrict__ bias, u16* __restrict__ out, int ldc,
    const u16* A2, const u16* B2, const float* bias2, u16* out2) {
  if (blockIdx.z) { A = A2; B = B2; bias = bias2; out = out2; }
  __shared__ u16 lds[3][3][128][32];  // [buf][slot: A,B0,B1][row][k]
  int tid = threadIdx.x, lane = tid & 63, wid = tid >> 6;
  int wm = wid >> 2, wn = wid & 3;
  int rsel = lane & 15, rgrp = lane >> 4;

  int nwg = gridDim.x * gridDim.y;
  int fid = blockIdx.y * gridDim.x + blockIdx.x;
  int chunk = nwg >> 3;
  int s = (fid & 7) * chunk + (fid >> 3);
  int mtile = s % mtiles, ntile = s / mtiles;
  int mrow0 = mtile * 128;
  int ncol0 = ntile * 256;

  int strow = wid * 16 + (lane >> 2);
  int stch = (lane & 3) ^ ((lane >> 3) & 3);

  auto stage = [&](int sbuf, int slot, int kt) {
    int grow = (slot == 0 ? mrow0 : ncol0 + (slot - 1) * 128) + strow;
    const u16* g = (slot == 0 ? A : B) + (size_t)grow * K + kt * 32 + stch * 8;
    gload16(g, &lds[sbuf][slot][wid * 16][0]);
  };

  f32x4 acc[2][4][2] = {};
  bf16x8 afr[4], bfr[2][2];

  auto rdAll = [&](int buf) {
#pragma unroll
    for (int mf = 0; mf < 4; ++mf) {
      int row = wm * 64 + mf * 16 + rsel;
      afr[mf] = *reinterpret_cast<const bf16x8*>(
          &lds[buf][0][row][(rgrp ^ ((row >> 1) & 3)) * 8]);
    }
#pragma unroll
    for (int bh = 0; bh < 2; ++bh)
#pragma unroll
      for (int nf = 0; nf < 2; ++nf) {
        int row = wn * 32 + nf * 16 + rsel;
        bfr[bh][nf] = *reinterpret_cast<const bf16x8*>(
            &lds[buf][1 + bh][row][(rgrp ^ ((row >> 1) & 3)) * 8]);
      }
  };
  auto mm16 = [&]() {
#pragma unroll
    for (int bh = 0; bh < 2; ++bh)
#pragma unroll
      for (int mf = 0; mf < 4; ++mf)
#pragma unroll
        for (int nf = 0; nf < 2; ++nf)
          acc[bh][mf][nf] = __builtin_amdgcn_mfma_f32_16x16x32_bf16(
              afr[mf], bfr[bh][nf], acc[bh][mf][nf], 0, 0, 0);
  };

  int nkt = K / 32;
  stage(0, 0, 0); stage(0, 1, 0); stage(0, 2, 0);
  stage(1, 0, 1); stage(1, 1, 1); stage(1, 2, 1);
  asm volatile("s_waitcnt vmcnt(3)" ::: "memory");  // t0 landed
  __builtin_amdgcn_s_barrier();

  int cur = 0;
  for (int t = 0; t < nkt; ++t) {
    rdAll(cur);
    int tn = (t + 2 < nkt) ? t + 2 : nkt - 1;  // clamped junk: never read
    int nb = cur + 2; if (nb >= 3) nb -= 3;
    stage(nb, 0, tn); stage(nb, 1, tn); stage(nb, 2, tn);
    __builtin_amdgcn_s_setprio(1); mm16(); __builtin_amdgcn_s_setprio(0);
    asm volatile("s_waitcnt vmcnt(3)" ::: "memory");  // tile t+1 landed
    __builtin_amdgcn_s_barrier();
    cur = (cur + 1 == 3) ? 0 : cur + 1;
  }

#pragma unroll
  for (int bh = 0; bh < 2; ++bh)
#pragma unroll
    for (int mf = 0; mf < 4; ++mf)
#pragma unroll
      for (int nf = 0; nf < 2; ++nf)
#pragma unroll
        for (int r = 0; r < 4; ++r) {
          int rl = mrow0 + wm * 64 + mf * 16 + rgrp * 4 + r;
          int cl = ncol0 + bh * 128 + wn * 32 + nf * 16 + rsel;
          float v = tanhf(acc[bh][mf][nf][r] + bias[cl]);
          out[(size_t)rl * ldc + cl] = f2b(v);
        }
}

// ---------------- unified bf16 MFMA GEMM: C = A * B^T ----------------------
// 2-phase dbuf. MODE 2: feat (gather, bias+relu, f32+bf16). MODE 3: vu.
#define TILE 128
#define BK 32

template <int MODE>
__global__ __launch_bounds__(256) void gemm2_k(
    const u16* __restrict__ Abf, const u16* __restrict__ Bbf, int lda, int ldb,
    int K, int Mreal, const float* __restrict__ bias,
    const u32* __restrict__ gidx, float* __restrict__ outf,
    u16* __restrict__ outb, int ldc,
    const u16* Abf2, const u16* Bbf2, const float* bias2,
    float* outf2, u16* outb2) {
  if (blockIdx.z) {
    if (Abf2) Abf = Abf2;
    if (Bbf2) Bbf = Bbf2;
    if (bias2) bias = bias2;
    if (outf2) outf = outf2;
    if (outb2) outb = outb2;
  }
  __shared__ u16 As[2][TILE][BK];
  __shared__ u16 Bs[2][TILE][BK];
  int tid = threadIdx.x, lane = tid & 63, wid = tid >> 6;
  int mt = blockIdx.x, nt2 = blockIdx.y;
  int row0 = (wid >> 1) * 64, col0 = (wid & 1) * 64;

  int scol = (lane & 3) * 8;
  const u16* gA[2];
  const u16* gB[2];
#pragma unroll
  for (int h = 0; h < 2; ++h) {
    int rA = (wid * 2 + h) * 16 + (lane >> 2);
    int grow = mt * TILE + rA;
    int arow;
    if (MODE == 2) arow = (int)gidx[grow < Mreal ? grow : 0];
    else arow = grow;
    gA[h] = Abf + (size_t)arow * lda + scol;
    int bcol = nt2 * TILE + rA;
    gB[h] = Bbf + (size_t)bcol * ldb + scol;
  }

  auto stage = [&](int buf, int kt) {
#pragma unroll
    for (int h = 0; h < 2; ++h) {
      gload16(gA[h] + kt, &As[buf][(wid * 2 + h) * 16][0]);
      gload16(gB[h] + kt, &Bs[buf][(wid * 2 + h) * 16][0]);
    }
  };

  f32x4 acc[4][4] = {};
  int k8 = 8 * (lane >> 4), rsel = lane & 15;
  int nkt = K / BK;

  stage(0, 0);
  __syncthreads();
  int cur = 0;
  for (int t = 0; t < nkt; ++t) {
    if (t + 1 < nkt) stage(cur ^ 1, (t + 1) * BK);
    bf16x8 a[4], b[4];
#pragma unroll
    for (int m = 0; m < 4; ++m)
      a[m] = *reinterpret_cast<const bf16x8*>(&As[cur][row0 + m * 16 + rsel][k8]);
#pragma unroll
    for (int n = 0; n < 4; ++n)
      b[n] = *reinterpret_cast<const bf16x8*>(&Bs[cur][col0 + n * 16 + rsel][k8]);
    __builtin_amdgcn_s_setprio(1);
#pragma unroll
    for (int m = 0; m < 4; ++m)
#pragma unroll
      for (int n = 0; n < 4; ++n)
        acc[m][n] = __builtin_amdgcn_mfma_f32_16x16x32_bf16(a[m], b[n], acc[m][n], 0, 0, 0);
    __builtin_amdgcn_s_setprio(0);
    __syncthreads();
    cur ^= 1;
  }

  int rgrp = lane >> 4, csel = lane & 15;
#pragma unroll
  for (int m = 0; m < 4; ++m)
#pragma unroll
    for (int n = 0; n < 4; ++n)
#pragma unroll
      for (int r = 0; r < 4; ++r) {
        int grow = mt * TILE + row0 + m * 16 + rgrp * 4 + r;
        int gcol = nt2 * TILE + col0 + n * 16 + csel;
        float v = acc[m][n][r];
        if (MODE == 2) {
          if (grow < Mreal) {
            v = fmaxf(v + bias[gcol], 0.f);
            outf[(size_t)grow * ldc + gcol] = v;
            outb[(size_t)grow * ldc + gcol] = f2b(v);
          }
        } else {
          if (grow < Mreal) outf[(size_t)grow * ldc + gcol] = v + bias[gcol];
        }
      }
}

// ---------------- per-row inverse L2 norm of bf16 matrix -------------------
__global__ __launch_bounds__(256) void norm_k(const u16* __restrict__ qb,
                                              float* __restrict__ inv, int rows, int dcols) {
  int gw = (int)((blockIdx.x * 256 + threadIdx.x) >> 6);
  int lane = threadIdx.x & 63;
  if (gw >= rows) return;
  const u16* r = qb + (size_t)gw * dcols;
  float s = 0.f;
  for (int c = lane; c < dcols; c += 64) { float v = b2f(r[c]); s += v * v; }
  for (int o = 32; o; o >>= 1) s += __shfl_down(s, o);
  if (lane == 0) inv[gw] = 1.f / fmaxf(sqrtf(s), 1e-12f);
}

// ===== per-row top-100 mean: lane-salted LDS histogram radix select ========
// Packed SIMD-in-register monotonic convert (5 ops / 2 keys).
__global__ __launch_bounds__(256) void topk_k(const u16* __restrict__ Ablk,
                                              float* __restrict__ A1, int rowbase) {
  __shared__ u32 hist[16][257];
  __shared__ u32 histlo[8][257];
  __shared__ u32 chist[256];
  __shared__ u32 sfx[257];
  __shared__ float wsfx[257];
  __shared__ float wsum[4];
  __shared__ int s_bhi;
  __shared__ u32 s_above;
  __shared__ float s_tail;
  int row = blockIdx.x, tid = threadIdx.x, wid = tid >> 6, lane = tid & 63;
  const uint4* src4 = reinterpret_cast<const uint4*>(Ablk + (size_t)row * 16384);
  uint4 regs[8];
#pragma unroll
  for (int v = 0; v < 8; ++v) regs[v] = src4[v * 256 + tid];
  for (int i = tid; i < 16 * 257; i += 256) (&hist[0][0])[i] = 0;
  for (int i = tid; i < 8 * 257; i += 256) (&histlo[0][0])[i] = 0;
  // packed monotonic convert: per half, neg -> ~x, pos -> x|0x8000
#pragma unroll
  for (int v = 0; v < 8; ++v) {
    u32* w = reinterpret_cast<u32*>(&regs[v]);
#pragma unroll
    for (int h = 0; h < 4; ++h) {
      u32 x = w[h];
      w[h] = x ^ ((((x & 0x80008000u) >> 15) * 0x7fffu) | 0x80008000u);
    }
  }
  __syncthreads();

  u32* myh = &hist[lane & 15][0];
#pragma unroll
  for (int v = 0; v < 8; ++v) {
    const u32* w = reinterpret_cast<const u32*>(&regs[v]);
#pragma unroll
    for (int h = 0; h < 4; ++h) {
      atomicAdd(&myh[(w[h] >> 8) & 0xffu], 1u);
      atomicAdd(&myh[w[h] >> 24], 1u);
    }
  }
  __syncthreads();
  {
    u32 c = 0;
#pragma unroll
    for (int j = 0; j < 16; ++j) c += hist[j][tid];
    sfx[tid] = c;
    if (tid == 0) sfx[256] = 0;
  }
  __syncthreads();
#pragma unroll
  for (int st = 1; st < 256; st <<= 1) {
    u32 add = (tid + st < 256) ? sfx[tid + st] : 0u;
    __syncthreads();
    sfx[tid] += add;
    __syncthreads();
  }
  if (sfx[tid] >= 100u && sfx[tid + 1] < 100u) {
    s_bhi = tid;
    s_above = sfx[tid + 1];
  }
  __syncthreads();
  u32 bhi = (u32)s_bhi, above = s_above;

  u32* myl = &histlo[lane & 7][0];
  float lsum = 0.f;
#pragma unroll
  for (int v = 0; v < 8; ++v) {
    const u32* w = reinterpret_cast<const u32*>(&regs[v]);
#pragma unroll
    for (int h = 0; h < 4; ++h) {
#pragma unroll
      for (int half = 0; half < 2; ++half) {
        u32 k = (w[h] >> (half * 16)) & 0xffffu;
        u32 hb = k >> 8;
        if (hb > bhi) lsum += key2f(k);
        else if (hb == bhi) atomicAdd(&myl[k & 0xffu], 1u);
      }
    }
  }
  for (int o = 32; o; o >>= 1) lsum += __shfl_down(lsum, o);
  if (lane == 0) wsum[wid] = lsum;
  __syncthreads();
  {
    u32 c = 0;
#pragma unroll
    for (int j = 0; j < 8; ++j) c += histlo[j][tid];
    chist[tid] = c;
    sfx[tid] = c;
    wsfx[tid] = (float)c * key2f((bhi << 8) | (u32)tid);
    if (tid == 0) { sfx[256] = 0; wsfx[256] = 0.f; }
  }
  __syncthreads();
#pragma unroll
  for (int st = 1; st < 256; st <<= 1) {
    u32 a = (tid + st < 256) ? sfx[tid + st] : 0u;
    float b = (tid + st < 256) ? wsfx[tid + st] : 0.f;
    __syncthreads();
    sfx[tid] += a;
    wsfx[tid] += b;
    __syncthreads();
  }
  {
    u32 need = 100u - above;
    if (sfx[tid] >= need && sfx[tid + 1] < need) {
      s_tail = wsfx[tid + 1] +
               (float)(need - sfx[tid + 1]) * key2f((bhi << 8) | (u32)tid);
    }
  }
  __syncthreads();
  if (tid == 0) {
    float tot = wsum[0] + wsum[1] + wsum[2] + wsum[3];
    A1[rowbase + row] = (tot + s_tail) * 0.01f;
  }
}

// ---------------- exact stable argsort: 2D partial counting rank -----------
__global__ __launch_bounds__(256) void rankpart_k(const float* __restrict__ A1,
                                                  u32* __restrict__ rank) {
  __shared__ u64 tile[1024];
  int i = blockIdx.x * 256 + threadIdx.x;
  int t0 = blockIdx.y * 1024;
  u64 my = makekey(A1[i], i);
  for (int j = threadIdx.x; j < 1024; j += 256) tile[j] = makekey(A1[t0 + j], t0 + j);
  __syncthreads();
  u32 r = 0;
  for (int j = 0; j < 1024; ++j) r += (tile[j] < my) ? 1u : 0u;
  atomicAdd(&rank[i], r);
}

__global__ __launch_bounds__(256) void scatter_k(const u32* __restrict__ rank,
                                                 u32* __restrict__ sortidx) {
  int i = blockIdx.x * 256 + threadIdx.x;
  sortidx[rank[i]] = (u32)i;
}

// ---------------- att logits z_i and g_i = feat_i . Wc ---------------------
__global__ __launch_bounds__(256) void attlogit_k(const float* __restrict__ avr,
                                                  const float* __restrict__ aur,
                                                  const float* __restrict__ featf,
                                                  const float* __restrict__ Wa,
                                                  const float* __restrict__ Wc,
                                                  float* __restrict__ z, float* __restrict__ g,
                                                  int M) {
  int gw = (int)((blockIdx.x * 256 + threadIdx.x) >> 6);
  int lane = threadIdx.x & 63;
  if (gw >= M) return;
  float s = 0.f;
  for (int c = lane; c < 256; c += 64) {
    float a = tanhf(avr[(size_t)gw * 256 + c]);
    float u = 1.f / (1.f + expf(-aur[(size_t)gw * 256 + c]));
    s += a * u * Wa[c];
  }
  float t = 0.f;
  for (int c = lane; c < 512; c += 64) t += featf[(size_t)gw * 512 + c] * Wc[c];
  for (int o = 32; o; o >>= 1) {
    s += __shfl_down(s, o);
    t += __shfl_down(t, o);
  }
  if (lane == 0) {
    z[gw] = s;
    g[gw] = t;
  }
}

// ---------------- softmax + outputs ----------------------------------------
__global__ __launch_bounds__(1024) void final_k(const float* __restrict__ z,
                                                const float* __restrict__ g,
                                                const float* __restrict__ bc,
                                                float* __restrict__ out, int M) {
  __shared__ float sred[16], s1[16], s2[16];
  int tid = threadIdx.x, lane = tid & 63, w = tid >> 6;
  float m = -1e30f;
  for (int i = tid; i < M; i += 1024) m = fmaxf(m, z[i]);
  for (int o = 32; o; o >>= 1) m = fmaxf(m, __shfl_down(m, o));
  if (lane == 0) sred[w] = m;
  __syncthreads();
  if (w == 0) {
    float t = (lane < 16) ? sred[lane] : -1e30f;
    for (int o = 8; o; o >>= 1) t = fmaxf(t, __shfl_down(t, o));
    if (lane == 0) sred[0] = t;
  }
  __syncthreads();
  m = sred[0];
  float se = 0.f, sg = 0.f;
  for (int i = tid; i < M; i += 1024) {
    float e = expf(z[i] - m);
    se += e;
    sg += e * g[i];
  }
  for (int o = 32; o; o >>= 1) {
    se += __shfl_down(se, o);
    sg += __shfl_down(sg, o);
  }
  if (lane == 0) {
    s1[w] = se;
    s2[w] = sg;
  }
  __syncthreads();
  if (w == 0) {
    float a = (lane < 16) ? s1[lane] : 0.f;
    float b = (lane < 16) ? s2[lane] : 0.f;
    for (int o = 8; o; o >>= 1) {
      a += __shfl_down(a, o);
      b += __shfl_down(b, o);
    }
    if (lane == 0) {
      s1[0] = a;
      s2[0] = b;
    }
  }
  __syncthreads();
  float inv = 1.f / s1[0];
  for (int i = tid; i < M; i += 1024) out[1 + i] = expf(z[i] - m) * inv;
  if (tid == 0) out[0] = s2[0] * inv + bc[0];
}

extern "C" void kernel_launch(void* const* d_in, const int* in_sizes, int n_in,
                              void* d_out, int out_size, void* d_ws, size_t ws_size,
                              hipStream_t stream) {
  const int N = 16384, D = 1024, HD = 512, HD2 = 256, MSEL = 4915;
  const float* x0 = (const float*)d_in[0];
  const float* x1 = (const float*)d_in[1];
  const float* Wq = (const float*)d_in[2];
  const float* bq = (const float*)d_in[3];
  const float* Wk = (const float*)d_in[4];
  const float* bk = (const float*)d_in[5];
  const float* W1 = (const float*)d_in[6];
  const float* b1 = (const float*)d_in[7];
  const float* Wv = (const float*)d_in[8];
  const float* bv = (const float*)d_in[9];
  const float* Wu = (const float*)d_in[10];
  const float* bu = (const float*)d_in[11];
  const float* Wa = (const float*)d_in[12];
  // d_in[13] = ba: softmax shift-invariant -> unused
  const float* Wc = (const float*)d_in[14];
  const float* bc = (const float*)d_in[15];
  float* out = (float*)d_out;

  char* base = (char*)d_ws;
  size_t off = 0;
  auto alloc = [&](size_t b) {
    void* r = base + off;
    off = (off + b + 255) & ~(size_t)255;
    return r;
  };
  const int MPAD = 4992;  // 39*128
  u16* wqt = (u16*)alloc((size_t)HD * D * 2);
  u16* wkt = (u16*)alloc((size_t)HD * D * 2);
  u16* w1t = (u16*)alloc((size_t)HD * D * 2);
  u16* wvt = (u16*)alloc((size_t)HD2 * HD * 2);
  u16* wut = (u16*)alloc((size_t)HD2 * HD * 2);
  u16* x0b = (u16*)alloc((size_t)N * D * 2);
  u16* x1b = (u16*)alloc((size_t)N * D * 2);
  u16* qb = (u16*)alloc((size_t)N * HD * 2);
  u16* kb = (u16*)alloc((size_t)N * HD * 2);
  float* invq = (float*)alloc((size_t)N * 4);
  float* invk = (float*)alloc((size_t)N * 4);
  float* A1 = (float*)alloc((size_t)N * 4);
  u32* rankbuf = (u32*)alloc((size_t)N * 4);
  u32* sortidx = (u32*)alloc((size_t)N * 4);
  float* featf = (float*)alloc((size_t)MPAD * HD * 4);
  u16* featb = (u16*)alloc((size_t)MPAD * HD * 2);
  float* avr = (float*)alloc((size_t)MPAD * HD2 * 4);
  float* aur = (float*)alloc((size_t)MPAD * HD2 * 4);
  float* zbuf = (float*)alloc((size_t)MPAD * 4);
  float* gbuf = (float*)alloc((size_t)MPAD * 4);
  // score slab: prefer 8192 rows; shrink if ws short
  int ablk = 8192;
  while (ablk > 256 && off + (size_t)ablk * N * 2 > ws_size) ablk >>= 1;
  u16* Ablk = (u16*)alloc((size_t)ablk * N * 2);

  // 1) convert inputs + weights to bf16
  conv_k<<<dim3((N * D / 8 + 255) / 256, 2), 256, 0, stream>>>(
      x0, x0b, x1, x1b, N * D / 8);
  convt_k<<<dim3(D / 32, HD / 32), 256, 0, stream>>>(Wq, wqt, D, HD);
  convt_k<<<dim3(D / 32, HD / 32), 256, 0, stream>>>(Wk, wkt, D, HD);
  convt_k<<<dim3(D / 32, HD / 32), 256, 0, stream>>>(W1, w1t, D, HD);
  convt_k<<<dim3(HD / 32, HD2 / 32), 256, 0, stream>>>(Wv, wvt, HD, HD2);
  convt_k<<<dim3(HD / 32, HD2 / 32), 256, 0, stream>>>(Wu, wut, HD, HD2);

  // 2) projections fused (3-buffer 128x256, 512 blocks): z=0 -> q, z=1 -> k
  mm8p_k<<<dim3(4, 64, 2), 512, 0, stream>>>(
      x0b, wqt, D, 128, bq, qb, HD, x1b, wkt, bk, kb);

  // 3) row inverse norms
  norm_k<<<N / 4, 256, 0, stream>>>(qb, invq, N, HD);
  norm_k<<<N / 4, 256, 0, stream>>>(kb, invk, N, HD);

  // 4) blocked score GEMM (4-phase 256^2) + per-row top-100 mean
  for (int it = 0; it < N / ablk; ++it) {
    mm8_k<1><<<dim3(ablk / 256, 64), 512, 0, stream>>>(
        qb, kb, HD, it * ablk, ablk / 256, invq, invk, nullptr, Ablk, N);
    topk_k<<<ablk, 256, 0, stream>>>(Ablk, A1, it * ablk);
  }

  // 5) exact stable ascending argsort of A1 (partial ranks + scatter)
  hipMemsetAsync(rankbuf, 0, (size_t)N * 4, stream);
  rankpart_k<<<dim3(N / 256, 16), 256, 0, stream>>>(A1, rankbuf);
  scatter_k<<<N / 256, 256, 0, stream>>>(rankbuf, sortidx);

  // 6) feat = relu(x0[sel] W1 + b1)  (f32 + bf16 out)
  gemm2_k<2><<<dim3((MSEL + TILE - 1) / TILE, HD / TILE), 256, 0, stream>>>(
      x0b, w1t, D, D, D, MSEL, b1, sortidx, featf, featb, HD,
      nullptr, nullptr, nullptr, nullptr, nullptr);

  // 7) fused: z=0 -> av_raw = feat Wv + bv ; z=1 -> au_raw = feat Wu + bu
  gemm2_k<3><<<dim3((MSEL + TILE - 1) / TILE, HD2 / TILE, 2), 256, 0, stream>>>(
      featb, wvt, HD, HD, HD, MSEL, bv, nullptr, avr, nullptr, HD2,
      nullptr, wut, bu, aur, nullptr);

  // 8) logits + per-row feat.Wc
  attlogit_k<<<(MSEL + 3) / 4, 256, 0, stream>>>(avr, aur, featf, Wa, Wc, zbuf, gbuf, MSEL);

  // 9) softmax + outputs
  final_k<<<1, 1024, 0, stream>>>(zbuf, gbuf, bc, out, MSEL);
}

// Round 16
// 682.589 us; speedup vs baseline: 1.3584x; 1.0167x over previous
//
#include <hip/hip_runtime.h>

typedef unsigned short u16;
typedef unsigned int u32;
typedef unsigned long long u64;

typedef __attribute__((ext_vector_type(8))) short bf16x8;
typedef __attribute__((ext_vector_type(4))) float f32x4;

__device__ __forceinline__ u16 f2b(float f) {
  u32 u = __float_as_uint(f);
  u32 r = (u + 0x7fffu + ((u >> 16) & 1u)) >> 16;  // RNE
  return (u16)r;
}
__device__ __forceinline__ float b2f(u16 h) {
  return __uint_as_float(((u32)h) << 16);
}
__device__ __forceinline__ float key2f(u32 k) {
  u16 kk = (u16)k;
  u16 bits = (kk & 0x8000) ? (u16)(kk ^ 0x8000) : (u16)(~kk);
  return b2f(bits);
}
__device__ __forceinline__ u64 makekey(float f, int i) {
  u32 u = __float_as_uint(f);
  u = (u & 0x80000000u) ? ~u : (u | 0x80000000u);
  return ((u64)u << 32) | (u32)i;
}

__device__ __forceinline__ void gload16(const void* g, void* l) {
  __builtin_amdgcn_global_load_lds((const __attribute__((address_space(1))) void*)g,
                                   (__attribute__((address_space(3))) void*)l, 16, 0, 0);
}

// ------- fp32 -> bf16 convert (8 elems/thread); y selects (src,dst) --------
__global__ __launch_bounds__(256) void conv_k(const float* __restrict__ s0,
                                              u16* __restrict__ d0,
                                              const float* __restrict__ s1,
                                              u16* __restrict__ d1, int n8) {
  const float* s = blockIdx.y ? s1 : s0;
  u16* d = blockIdx.y ? d1 : d0;
  int i = blockIdx.x * 256 + threadIdx.x;
  if (i >= n8) return;
  const float4* s4 = reinterpret_cast<const float4*>(s);
  float4 f0 = s4[i * 2], f1 = s4[i * 2 + 1];
  __align__(16) u16 t[8];
  t[0] = f2b(f0.x); t[1] = f2b(f0.y); t[2] = f2b(f0.z); t[3] = f2b(f0.w);
  t[4] = f2b(f1.x); t[5] = f2b(f1.y); t[6] = f2b(f1.z); t[7] = f2b(f1.w);
  reinterpret_cast<uint4*>(d)[i] = *reinterpret_cast<uint4*>(t);
}

// -------- transpose+convert W (K x Nc fp32) -> Wt (Nc x K bf16), LDS-tiled -
__global__ __launch_bounds__(256) void convt_k(const float* __restrict__ W,
                                               u16* __restrict__ Wt, int K, int Nc) {
  __shared__ float t[32][33];
  int k0 = blockIdx.x * 32, n0 = blockIdx.y * 32;
  int c = threadIdx.x & 31, r4 = threadIdx.x >> 5;
#pragma unroll
  for (int i = 0; i < 4; ++i) {
    int r = r4 + i * 8;
    t[r][c] = W[(size_t)(k0 + r) * Nc + n0 + c];  // coalesced on c
  }
  __syncthreads();
#pragma unroll
  for (int i = 0; i < 4; ++i) {
    int r = r4 + i * 8;
    Wt[(size_t)(n0 + r) * K + k0 + c] = f2b(t[c][r]);  // coalesced on c
  }
}

// ================ 4-phase 256x256 MFMA GEMM (score) ========================
// 8 waves (512 thr), BK=32, LDS 64KB. SINGLE barrier per phase; counted
// vmcnt placed AFTER the MFMA cluster. r11/r14-best structure.
// MODE 1: score v*rs[row]*cs[col], bf16 out
template <int MODE>
__global__ __launch_bounds__(512, 2) void mm8_k(
    const u16* __restrict__ A, const u16* __restrict__ B, int K, int Mbase,
    int mtiles, const float* __restrict__ rs, const float* __restrict__ cs,
    const float* __restrict__ bias, u16* __restrict__ out, int ldc) {
  __shared__ u16 lds[2][2][2][128][32];  // [buf][mat][half][row][k]
  int tid = threadIdx.x, lane = tid & 63, wid = tid >> 6;
  int wm = wid >> 2, wn = wid & 3;
  int rsel = lane & 15, rgrp = lane >> 4;

  int nwg = gridDim.x * gridDim.y;
  int fid = blockIdx.y * gridDim.x + blockIdx.x;
  int chunk = nwg >> 3;
  int s = (fid & 7) * chunk + (fid >> 3);  // XCD-contiguous remap (nwg%8==0)
  int mtile = s % mtiles, ntile = s / mtiles;
  int mrow0 = Mbase + mtile * 256;
  int ncol0 = ntile * 256;

  int strow = wid * 16 + (lane >> 2);
  int stch = (lane & 3) ^ ((lane >> 3) & 3);  // pre-swizzled source chunk

  auto stage = [&](int sbuf, int smat, int shalf, int kt) {
    int grow = (smat ? ncol0 : mrow0) + shalf * 128 + strow;
    const u16* g = (smat ? B : A) + (size_t)grow * K + kt * 32 + stch * 8;
    gload16(g, &lds[sbuf][smat][shalf][wid * 16][0]);
  };

  f32x4 acc[4][4][2] = {};
  bf16x8 afr[4], bfr[2][2];

  auto rdA = [&](int buf, int ah) {
#pragma unroll
    for (int mf = 0; mf < 4; ++mf) {
      int row = wm * 64 + mf * 16 + rsel;
      afr[mf] = *reinterpret_cast<const bf16x8*>(
          &lds[buf][0][ah][row][(rgrp ^ ((row >> 1) & 3)) * 8]);
    }
  };
  auto rdB = [&](int buf) {
#pragma unroll
    for (int bh = 0; bh < 2; ++bh)
#pragma unroll
      for (int nf = 0; nf < 2; ++nf) {
        int row = wn * 32 + nf * 16 + rsel;
        bfr[bh][nf] = *reinterpret_cast<const bf16x8*>(
            &lds[buf][1][bh][row][(rgrp ^ ((row >> 1) & 3)) * 8]);
      }
  };
  auto mm = [&](int ah) {
#pragma unroll
    for (int bh = 0; bh < 2; ++bh)
#pragma unroll
      for (int mf = 0; mf < 4; ++mf)
#pragma unroll
        for (int nf = 0; nf < 2; ++nf)
          acc[ah * 2 + bh][mf][nf] = __builtin_amdgcn_mfma_f32_16x16x32_bf16(
              afr[mf], bfr[bh][nf], acc[ah * 2 + bh][mf][nf], 0, 0, 0);
  };

  int nkt = K / 32;
  stage(0, 0, 0, 0); stage(0, 1, 0, 0); stage(0, 1, 1, 0); stage(0, 0, 1, 0);
  stage(1, 0, 0, 1); stage(1, 1, 0, 1);
  asm volatile("s_waitcnt vmcnt(2)" ::: "memory");  // buf0 complete
  __builtin_amdgcn_s_barrier();

  for (int j = 0; j < nkt / 2; ++j) {
    int t1 = 2 * j + 1;
    int t2 = (2 * j + 2 < nkt) ? 2 * j + 2 : nkt - 1;  // clamped: never read
    int t3 = (2 * j + 3 < nkt) ? 2 * j + 3 : nkt - 1;
    rdB(0); rdA(0, 0);
    stage(1, 1, 1, t1); stage(1, 0, 1, t1);
    __builtin_amdgcn_s_setprio(1); mm(0); __builtin_amdgcn_s_setprio(0);
    __builtin_amdgcn_s_barrier();
    rdA(0, 1);
    stage(0, 0, 0, t2); stage(0, 1, 0, t2);
    __builtin_amdgcn_s_setprio(1); mm(1); __builtin_amdgcn_s_setprio(0);
    asm volatile("s_waitcnt vmcnt(2)" ::: "memory");
    __builtin_amdgcn_s_barrier();
    rdB(1); rdA(1, 0);
    stage(0, 1, 1, t2); stage(0, 0, 1, t2);
    __builtin_amdgcn_s_setprio(1); mm(0); __builtin_amdgcn_s_setprio(0);
    __builtin_amdgcn_s_barrier();
    rdA(1, 1);
    stage(1, 0, 0, t3); stage(1, 1, 0, t3);
    __builtin_amdgcn_s_setprio(1); mm(1); __builtin_amdgcn_s_setprio(0);
    asm volatile("s_waitcnt vmcnt(2)" ::: "memory");
    __builtin_amdgcn_s_barrier();
  }

#pragma unroll
  for (int q = 0; q < 4; ++q)
#pragma unroll
    for (int mf = 0; mf < 4; ++mf)
#pragma unroll
      for (int nf = 0; nf < 2; ++nf)
#pragma unroll
        for (int r = 0; r < 4; ++r) {
          int rl = mtile * 256 + (q >> 1) * 128 + wm * 64 + mf * 16 + rgrp * 4 + r;
          int cl = ncol0 + (q & 1) * 128 + wn * 32 + nf * 16 + rsel;
          float v = acc[q][mf][nf][r] * rs[Mbase + rl] * cs[cl];
          out[(size_t)rl * ldc + cl] = f2b(v);
        }
}

// ========== proj GEMM: 128x256 tile, 3-buffer, 16-MFMA phases ==============
// One phase per K-tile, SINGLE barrier. LDS 72KB -> 2 blocks/CU. r11-best.
__global__ __launch_bounds__(512, 2) void mm8p_k(
    const u16* __restrict__ A, const u16* __restrict__ B, int K, int mtiles,
    const float* __restrict__ bias, u16* __restrict__ out, int ldc,
    const u16* A2, const u16* B2, const float* bias2, u16* out2) {
  if (blockIdx.z) { A = A2; B = B2; bias = bias2; out = out2; }
  __shared__ u16 lds[3][3][128][32];  // [buf][slot: A,B0,B1][row][k]
  int tid = threadIdx.x, lane = tid & 63, wid = tid >> 6;
  int wm = wid >> 2, wn = wid & 3;
  int rsel = lane & 15, rgrp = lane >> 4;

  int nwg = gridDim.x * gridDim.y;
  int fid = blockIdx.y * gridDim.x + blockIdx.x;
  int chunk = nwg >> 3;
  int s = (fid & 7) * chunk + (fid >> 3);
  int mtile = s % mtiles, ntile = s / mtiles;
  int mrow0 = mtile * 128;
  int ncol0 = ntile * 256;

  int strow = wid * 16 + (lane >> 2);
  int stch = (lane & 3) ^ ((lane >> 3) & 3);

  auto stage = [&](int sbuf, int slot, int kt) {
    int grow = (slot == 0 ? mrow0 : ncol0 + (slot - 1) * 128) + strow;
    const u16* g = (slot == 0 ? A : B) + (size_t)grow * K + kt * 32 + stch * 8;
    gload16(g, &lds[sbuf][slot][wid * 16][0]);
  };

  f32x4 acc[2][4][2] = {};
  bf16x8 afr[4], bfr[2][2];

  auto rdAll = [&](int buf) {
#pragma unroll
    for (int mf = 0; mf < 4; ++mf) {
      int row = wm * 64 + mf * 16 + rsel;
      afr[mf] = *reinterpret_cast<const bf16x8*>(
          &lds[buf][0][row][(rgrp ^ ((row >> 1) & 3)) * 8]);
    }
#pragma unroll
    for (int bh = 0; bh < 2; ++bh)
#pragma unroll
      for (int nf = 0; nf < 2; ++nf) {
        int row = wn * 32 + nf * 16 + rsel;
        bfr[bh][nf] = *reinterpret_cast<const bf16x8*>(
            &lds[buf][1 + bh][row][(rgrp ^ ((row >> 1) & 3)) * 8]);
      }
  };
  auto mm16 = [&]() {
#pragma unroll
    for (int bh = 0; bh < 2; ++bh)
#pragma unroll
      for (int mf = 0; mf < 4; ++mf)
#pragma unroll
        for (int nf = 0; nf < 2; ++nf)
          acc[bh][mf][nf] = __builtin_amdgcn_mfma_f32_16x16x32_bf16(
              afr[mf], bfr[bh][nf], acc[bh][mf][nf], 0, 0, 0);
  };

  int nkt = K / 32;
  stage(0, 0, 0); stage(0, 1, 0); stage(0, 2, 0);
  stage(1, 0, 1); stage(1, 1, 1); stage(1, 2, 1);
  asm volatile("s_waitcnt vmcnt(3)" ::: "memory");  // t0 landed
  __builtin_amdgcn_s_barrier();

  int cur = 0;
  for (int t = 0; t < nkt; ++t) {
    rdAll(cur);
    int tn = (t + 2 < nkt) ? t + 2 : nkt - 1;  // clamped junk: never read
    int nb = cur + 2; if (nb >= 3) nb -= 3;
    stage(nb, 0, tn); stage(nb, 1, tn); stage(nb, 2, tn);
    __builtin_amdgcn_s_setprio(1); mm16(); __builtin_amdgcn_s_setprio(0);
    asm volatile("s_waitcnt vmcnt(3)" ::: "memory");  // tile t+1 landed
    __builtin_amdgcn_s_barrier();
    cur = (cur + 1 == 3) ? 0 : cur + 1;
  }

#pragma unroll
  for (int bh = 0; bh < 2; ++bh)
#pragma unroll
    for (int mf = 0; mf < 4; ++mf)
#pragma unroll
      for (int nf = 0; nf < 2; ++nf)
#pragma unroll
        for (int r = 0; r < 4; ++r) {
          int rl = mrow0 + wm * 64 + mf * 16 + rgrp * 4 + r;
          int cl = ncol0 + bh * 128 + wn * 32 + nf * 16 + rsel;
          float v = tanhf(acc[bh][mf][nf][r] + bias[cl]);
          out[(size_t)rl * ldc + cl] = f2b(v);
        }
}

// ---------------- unified bf16 MFMA GEMM: C = A * B^T ----------------------
// 2-phase dbuf. MODE 2: feat (gather, bias+relu, f32+bf16). MODE 3: vu.
#define TILE 128
#define BK 32

template <int MODE>
__global__ __launch_bounds__(256) void gemm2_k(
    const u16* __restrict__ Abf, const u16* __restrict__ Bbf, int lda, int ldb,
    int K, int Mreal, const float* __restrict__ bias,
    const u32* __restrict__ gidx, float* __restrict__ outf,
    u16* __restrict__ outb, int ldc,
    const u16* Abf2, const u16* Bbf2, const float* bias2,
    float* outf2, u16* outb2) {
  if (blockIdx.z) {
    if (Abf2) Abf = Abf2;
    if (Bbf2) Bbf = Bbf2;
    if (bias2) bias = bias2;
    if (outf2) outf = outf2;
    if (outb2) outb = outb2;
  }
  __shared__ u16 As[2][TILE][BK];
  __shared__ u16 Bs[2][TILE][BK];
  int tid = threadIdx.x, lane = tid & 63, wid = tid >> 6;
  int mt = blockIdx.x, nt2 = blockIdx.y;
  int row0 = (wid >> 1) * 64, col0 = (wid & 1) * 64;

  int scol = (lane & 3) * 8;
  const u16* gA[2];
  const u16* gB[2];
#pragma unroll
  for (int h = 0; h < 2; ++h) {
    int rA = (wid * 2 + h) * 16 + (lane >> 2);
    int grow = mt * TILE + rA;
    int arow;
    if (MODE == 2) arow = (int)gidx[grow < Mreal ? grow : 0];
    else arow = grow;
    gA[h] = Abf + (size_t)arow * lda + scol;
    int bcol = nt2 * TILE + rA;
    gB[h] = Bbf + (size_t)bcol * ldb + scol;
  }

  auto stage = [&](int buf, int kt) {
#pragma unroll
    for (int h = 0; h < 2; ++h) {
      gload16(gA[h] + kt, &As[buf][(wid * 2 + h) * 16][0]);
      gload16(gB[h] + kt, &Bs[buf][(wid * 2 + h) * 16][0]);
    }
  };

  f32x4 acc[4][4] = {};
  int k8 = 8 * (lane >> 4), rsel = lane & 15;
  int nkt = K / BK;

  stage(0, 0);
  __syncthreads();
  int cur = 0;
  for (int t = 0; t < nkt; ++t) {
    if (t + 1 < nkt) stage(cur ^ 1, (t + 1) * BK);
    bf16x8 a[4], b[4];
#pragma unroll
    for (int m = 0; m < 4; ++m)
      a[m] = *reinterpret_cast<const bf16x8*>(&As[cur][row0 + m * 16 + rsel][k8]);
#pragma unroll
    for (int n = 0; n < 4; ++n)
      b[n] = *reinterpret_cast<const bf16x8*>(&Bs[cur][col0 + n * 16 + rsel][k8]);
    __builtin_amdgcn_s_setprio(1);
#pragma unroll
    for (int m = 0; m < 4; ++m)
#pragma unroll
      for (int n = 0; n < 4; ++n)
        acc[m][n] = __builtin_amdgcn_mfma_f32_16x16x32_bf16(a[m], b[n], acc[m][n], 0, 0, 0);
    __builtin_amdgcn_s_setprio(0);
    __syncthreads();
    cur ^= 1;
  }

  int rgrp = lane >> 4, csel = lane & 15;
#pragma unroll
  for (int m = 0; m < 4; ++m)
#pragma unroll
    for (int n = 0; n < 4; ++n)
#pragma unroll
      for (int r = 0; r < 4; ++r) {
        int grow = mt * TILE + row0 + m * 16 + rgrp * 4 + r;
        int gcol = nt2 * TILE + col0 + n * 16 + csel;
        float v = acc[m][n][r];
        if (MODE == 2) {
          if (grow < Mreal) {
            v = fmaxf(v + bias[gcol], 0.f);
            outf[(size_t)grow * ldc + gcol] = v;
            outb[(size_t)grow * ldc + gcol] = f2b(v);
          }
        } else {
          if (grow < Mreal) outf[(size_t)grow * ldc + gcol] = v + bias[gcol];
        }
      }
}

// ---------------- per-row inverse L2 norm of bf16 matrix -------------------
__global__ __launch_bounds__(256) void norm_k(const u16* __restrict__ qb,
                                              float* __restrict__ inv, int rows, int dcols) {
  int gw = (int)((blockIdx.x * 256 + threadIdx.x) >> 6);
  int lane = threadIdx.x & 63;
  if (gw >= rows) return;
  const u16* r = qb + (size_t)gw * dcols;
  float s = 0.f;
  for (int c = lane; c < dcols; c += 64) { float v = b2f(r[c]); s += v * v; }
  for (int o = 32; o; o >>= 1) s += __shfl_down(s, o);
  if (lane == 0) inv[gw] = 1.f / fmaxf(sqrtf(s), 1e-12f);
}

// ===== per-row top-100 mean: lane-salted LDS histogram radix select ========
// Threshold scans done as wave-0 REGISTER suffix scans (no barriers).
__global__ __launch_bounds__(256) void topk_k(const u16* __restrict__ Ablk,
                                              float* __restrict__ A1, int rowbase) {
  __shared__ u32 hist[16][257];
  __shared__ u32 histlo[8][257];
  __shared__ float wsum[4];
  __shared__ int s_bhi;
  __shared__ u32 s_above;
  __shared__ float s_tail;
  int row = blockIdx.x, tid = threadIdx.x, wid = tid >> 6, lane = tid & 63;
  const uint4* src4 = reinterpret_cast<const uint4*>(Ablk + (size_t)row * 16384);
  uint4 regs[8];
#pragma unroll
  for (int v = 0; v < 8; ++v) regs[v] = src4[v * 256 + tid];
  for (int i = tid; i < 16 * 257; i += 256) (&hist[0][0])[i] = 0;
  for (int i = tid; i < 8 * 257; i += 256) (&histlo[0][0])[i] = 0;
  // packed monotonic convert: per half, neg -> ~x, pos -> x|0x8000
#pragma unroll
  for (int v = 0; v < 8; ++v) {
    u32* w = reinterpret_cast<u32*>(&regs[v]);
#pragma unroll
    for (int h = 0; h < 4; ++h) {
      u32 x = w[h];
      w[h] = x ^ ((((x & 0x80008000u) >> 15) * 0x7fffu) | 0x80008000u);
    }
  }
  __syncthreads();

  // pass 1: high-byte histogram, 16 salted copies
  u32* myh = &hist[lane & 15][0];
#pragma unroll
  for (int v = 0; v < 8; ++v) {
    const u32* w = reinterpret_cast<const u32*>(&regs[v]);
#pragma unroll
    for (int h = 0; h < 4; ++h) {
      atomicAdd(&myh[(w[h] >> 8) & 0xffu], 1u);
      atomicAdd(&myh[w[h] >> 24], 1u);
    }
  }
  __syncthreads();
  // wave-0 register suffix scan over 256 bins (lane owns bins 4l..4l+3)
  if (wid == 0) {
    u32 c0 = 0, c1 = 0, c2 = 0, c3 = 0;
#pragma unroll
    for (int j = 0; j < 16; ++j) {
      c0 += hist[j][lane * 4 + 0];
      c1 += hist[j][lane * 4 + 1];
      c2 += hist[j][lane * 4 + 2];
      c3 += hist[j][lane * 4 + 3];
    }
    u32 t = c0 + c1 + c2 + c3;
    u32 acc = t;
#pragma unroll
    for (int o = 1; o < 64; o <<= 1) {
      u32 v = __shfl_down(acc, o);
      acc += ((lane + o) < 64) ? v : 0u;
    }
    u32 excl = acc - t;  // sum over lanes > lane
    u32 i3 = excl + c3, i2 = i3 + c2, i1 = i2 + c1, i0 = i1 + c0;
    if (i0 >= 100u && i1 < 100u) { s_bhi = lane * 4 + 0; s_above = i1; }
    if (i1 >= 100u && i2 < 100u) { s_bhi = lane * 4 + 1; s_above = i2; }
    if (i2 >= 100u && i3 < 100u) { s_bhi = lane * 4 + 2; s_above = i3; }
    if (i3 >= 100u && excl < 100u) { s_bhi = lane * 4 + 3; s_above = excl; }
  }
  __syncthreads();
  u32 bhi = (u32)s_bhi, above = s_above;

  // pass 2: register sum of keys above; low-byte hist of threshold bin
  u32* myl = &histlo[lane & 7][0];
  float lsum = 0.f;
#pragma unroll
  for (int v = 0; v < 8; ++v) {
    const u32* w = reinterpret_cast<const u32*>(&regs[v]);
#pragma unroll
    for (int h = 0; h < 4; ++h) {
#pragma unroll
      for (int half = 0; half < 2; ++half) {
        u32 k = (w[h] >> (half * 16)) & 0xffffu;
        u32 hb = k >> 8;
        if (hb > bhi) lsum += key2f(k);
        else if (hb == bhi) atomicAdd(&myl[k & 0xffu], 1u);
      }
    }
  }
  for (int o = 32; o; o >>= 1) lsum += __shfl_down(lsum, o);
  if (lane == 0) wsum[wid] = lsum;
  __syncthreads();
  // wave-0 register scan: (count, weighted) suffix over low-byte bins
  if (wid == 0) {
    u32 c[4];
    float wv[4];
#pragma unroll
    for (int q = 0; q < 4; ++q) {
      u32 cc = 0;
#pragma unroll
      for (int j = 0; j < 8; ++j) cc += histlo[j][lane * 4 + q];
      c[q] = cc;
      wv[q] = (float)cc * key2f((bhi << 8) | (u32)(lane * 4 + q));
    }
    u32 t = c[0] + c[1] + c[2] + c[3];
    float wt = wv[0] + wv[1] + wv[2] + wv[3];
    u32 acc = t;
    float wacc = wt;
#pragma unroll
    for (int o = 1; o < 64; o <<= 1) {
      u32 v = __shfl_down(acc, o);
      float fv = __shfl_down(wacc, o);
      bool ok = (lane + o) < 64;
      acc += ok ? v : 0u;
      wacc += ok ? fv : 0.f;
    }
    u32 excl = acc - t;
    float wexcl = wacc - wt;
    u32 i3 = excl + c[3], i2 = i3 + c[2], i1 = i2 + c[1], i0 = i1 + c[0];
    float w3 = wexcl + wv[3], w2 = w3 + wv[2], w1 = w2 + wv[1];
    u32 need = 100u - above;
    if (i0 >= need && i1 < need)
      s_tail = w1 + (float)(need - i1) * key2f((bhi << 8) | (u32)(lane * 4 + 0));
    if (i1 >= need && i2 < need)
      s_tail = w2 + (float)(need - i2) * key2f((bhi << 8) | (u32)(lane * 4 + 1));
    if (i2 >= need && i3 < need)
      s_tail = w3 + (float)(need - i3) * key2f((bhi << 8) | (u32)(lane * 4 + 2));
    if (i3 >= need && excl < need)
      s_tail = wexcl + (float)(need - excl) * key2f((bhi << 8) | (u32)(lane * 4 + 3));
  }
  __syncthreads();
  if (tid == 0) {
    float tot = wsum[0] + wsum[1] + wsum[2] + wsum[3];
    A1[rowbase + row] = (tot + s_tail) * 0.01f;
  }
}

// ---------------- exact stable argsort: 2D partial counting rank -----------
__global__ __launch_bounds__(256) void rankpart_k(const float* __restrict__ A1,
                                                  u32* __restrict__ rank) {
  __shared__ u64 tile[1024];
  int i = blockIdx.x * 256 + threadIdx.x;
  int t0 = blockIdx.y * 1024;
  u64 my = makekey(A1[i], i);
  for (int j = threadIdx.x; j < 1024; j += 256) tile[j] = makekey(A1[t0 + j], t0 + j);
  __syncthreads();
  u32 r = 0;
  for (int j = 0; j < 1024; ++j) r += (tile[j] < my) ? 1u : 0u;
  atomicAdd(&rank[i], r);
}

__global__ __launch_bounds__(256) void scatter_k(const u32* __restrict__ rank,
                                                 u32* __restrict__ sortidx) {
  int i = blockIdx.x * 256 + threadIdx.x;
  sortidx[rank[i]] = (u32)i;
}

// ---------------- att logits z_i and g_i = feat_i . Wc ---------------------
__global__ __launch_bounds__(256) void attlogit_k(const float* __restrict__ avr,
                                                  const float* __restrict__ aur,
                                                  const float* __restrict__ featf,
                                                  const float* __restrict__ Wa,
                                                  const float* __restrict__ Wc,
                                                  float* __restrict__ z, float* __restrict__ g,
                                                  int M) {
  int gw = (int)((blockIdx.x * 256 + threadIdx.x) >> 6);
  int lane = threadIdx.x & 63;
  if (gw >= M) return;
  float s = 0.f;
  for (int c = lane; c < 256; c += 64) {
    float a = tanhf(avr[(size_t)gw * 256 + c]);
    float u = 1.f / (1.f + expf(-aur[(size_t)gw * 256 + c]));
    s += a * u * Wa[c];
  }
  float t = 0.f;
  for (int c = lane; c < 512; c += 64) t += featf[(size_t)gw * 512 + c] * Wc[c];
  for (int o = 32; o; o >>= 1) {
    s += __shfl_down(s, o);
    t += __shfl_down(t, o);
  }
  if (lane == 0) {
    z[gw] = s;
    g[gw] = t;
  }
}

// ---------------- softmax + outputs ----------------------------------------
__global__ __launch_bounds__(1024) void final_k(const float* __restrict__ z,
                                                const float* __restrict__ g,
                                                const float* __restrict__ bc,
                                                float* __restrict__ out, int M) {
  __shared__ float sred[16], s1[16], s2[16];
  int tid = threadIdx.x, lane = tid & 63, w = tid >> 6;
  float m = -1e30f;
  for (int i = tid; i < M; i += 1024) m = fmaxf(m, z[i]);
  for (int o = 32; o; o >>= 1) m = fmaxf(m, __shfl_down(m, o));
  if (lane == 0) sred[w] = m;
  __syncthreads();
  if (w == 0) {
    float t = (lane < 16) ? sred[lane] : -1e30f;
    for (int o = 8; o; o >>= 1) t = fmaxf(t, __shfl_down(t, o));
    if (lane == 0) sred[0] = t;
  }
  __syncthreads();
  m = sred[0];
  float se = 0.f, sg = 0.f;
  for (int i = tid; i < M; i += 1024) {
    float e = expf(z[i] - m);
    se += e;
    sg += e * g[i];
  }
  for (int o = 32; o; o >>= 1) {
    se += __shfl_down(se, o);
    sg += __shfl_down(sg, o);
  }
  if (lane == 0) {
    s1[w] = se;
    s2[w] = sg;
  }
  __syncthreads();
  if (w == 0) {
    float a = (lane < 16) ? s1[lane] : 0.f;
    float b = (lane < 16) ? s2[lane] : 0.f;
    for (int o = 8; o; o >>= 1) {
      a += __shfl_down(a, o);
      b += __shfl_down(b, o);
    }
    if (lane == 0) {
      s1[0] = a;
      s2[0] = b;
    }
  }
  __syncthreads();
  float inv = 1.f / s1[0];
  for (int i = tid; i < M; i += 1024) out[1 + i] = expf(z[i] - m) * inv;
  if (tid == 0) out[0] = s2[0] * inv + bc[0];
}

extern "C" void kernel_launch(void* const* d_in, const int* in_sizes, int n_in,
                              void* d_out, int out_size, void* d_ws, size_t ws_size,
                              hipStream_t stream) {
  const int N = 16384, D = 1024, HD = 512, HD2 = 256, MSEL = 4915;
  const float* x0 = (const float*)d_in[0];
  const float* x1 = (const float*)d_in[1];
  const float* Wq = (const float*)d_in[2];
  const float* bq = (const float*)d_in[3];
  const float* Wk = (const float*)d_in[4];
  const float* bk = (const float*)d_in[5];
  const float* W1 = (const float*)d_in[6];
  const float* b1 = (const float*)d_in[7];
  const float* Wv = (const float*)d_in[8];
  const float* bv = (const float*)d_in[9];
  const float* Wu = (const float*)d_in[10];
  const float* bu = (const float*)d_in[11];
  const float* Wa = (const float*)d_in[12];
  // d_in[13] = ba: softmax shift-invariant -> unused
  const float* Wc = (const float*)d_in[14];
  const float* bc = (const float*)d_in[15];
  float* out = (float*)d_out;

  char* base = (char*)d_ws;
  size_t off = 0;
  auto alloc = [&](size_t b) {
    void* r = base + off;
    off = (off + b + 255) & ~(size_t)255;
    return r;
  };
  const int MPAD = 4992;  // 39*128
  u16* wqt = (u16*)alloc((size_t)HD * D * 2);
  u16* wkt = (u16*)alloc((size_t)HD * D * 2);
  u16* w1t = (u16*)alloc((size_t)HD * D * 2);
  u16* wvt = (u16*)alloc((size_t)HD2 * HD * 2);
  u16* wut = (u16*)alloc((size_t)HD2 * HD * 2);
  u16* x0b = (u16*)alloc((size_t)N * D * 2);
  u16* x1b = (u16*)alloc((size_t)N * D * 2);
  u16* qb = (u16*)alloc((size_t)N * HD * 2);
  u16* kb = (u16*)alloc((size_t)N * HD * 2);
  float* invq = (float*)alloc((size_t)N * 4);
  float* invk = (float*)alloc((size_t)N * 4);
  float* A1 = (float*)alloc((size_t)N * 4);
  u32* rankbuf = (u32*)alloc((size_t)N * 4);
  u32* sortidx = (u32*)alloc((size_t)N * 4);
  float* featf = (float*)alloc((size_t)MPAD * HD * 4);
  u16* featb = (u16*)alloc((size_t)MPAD * HD * 2);
  float* avr = (float*)alloc((size_t)MPAD * HD2 * 4);
  float* aur = (float*)alloc((size_t)MPAD * HD2 * 4);
  float* zbuf = (float*)alloc((size_t)MPAD * 4);
  float* gbuf = (float*)alloc((size_t)MPAD * 4);
  // score slab: prefer 8192 rows; shrink if ws short
  int ablk = 8192;
  while (ablk > 256 && off + (size_t)ablk * N * 2 > ws_size) ablk >>= 1;
  u16* Ablk = (u16*)alloc((size_t)ablk * N * 2);

  // 1) convert inputs + weights to bf16
  conv_k<<<dim3((N * D / 8 + 255) / 256, 2), 256, 0, stream>>>(
      x0, x0b, x1, x1b, N * D / 8);
  convt_k<<<dim3(D / 32, HD / 32), 256, 0, stream>>>(Wq, wqt, D, HD);
  convt_k<<<dim3(D / 32, HD / 32), 256, 0, stream>>>(Wk, wkt, D, HD);
  convt_k<<<dim3(D / 32, HD / 32), 256, 0, stream>>>(W1, w1t, D, HD);
  convt_k<<<dim3(HD / 32, HD2 / 32), 256, 0, stream>>>(Wv, wvt, HD, HD2);
  convt_k<<<dim3(HD / 32, HD2 / 32), 256, 0, stream>>>(Wu, wut, HD, HD2);

  // 2) projections fused (3-buffer 128x256, 512 blocks): z=0 -> q, z=1 -> k
  mm8p_k<<<dim3(4, 64, 2), 512, 0, stream>>>(
      x0b, wqt, D, 128, bq, qb, HD, x1b, wkt, bk, kb);

  // 3) row inverse norms
  norm_k<<<N / 4, 256, 0, stream>>>(qb, invq, N, HD);
  norm_k<<<N / 4, 256, 0, stream>>>(kb, invk, N, HD);

  // 4) blocked score GEMM (4-phase 256^2) + per-row top-100 mean
  for (int it = 0; it < N / ablk; ++it) {
    mm8_k<1><<<dim3(ablk / 256, 64), 512, 0, stream>>>(
        qb, kb, HD, it * ablk, ablk / 256, invq, invk, nullptr, Ablk, N);
    topk_k<<<ablk, 256, 0, stream>>>(Ablk, A1, it * ablk);
  }

  // 5) exact stable ascending argsort of A1 (partial ranks + scatter)
  hipMemsetAsync(rankbuf, 0, (size_t)N * 4, stream);
  rankpart_k<<<dim3(N / 256, 16), 256, 0, stream>>>(A1, rankbuf);
  scatter_k<<<N / 256, 256, 0, stream>>>(rankbuf, sortidx);

  // 6) feat = relu(x0[sel] W1 + b1)  (f32 + bf16 out)
  gemm2_k<2><<<dim3((MSEL + TILE - 1) / TILE, HD / TILE), 256, 0, stream>>>(
      x0b, w1t, D, D, D, MSEL, b1, sortidx, featf, featb, HD,
      nullptr, nullptr, nullptr, nullptr, nullptr);

  // 7) fused: z=0 -> av_raw = feat Wv + bv ; z=1 -> au_raw = feat Wu + bu
  gemm2_k<3><<<dim3((MSEL + TILE - 1) / TILE, HD2 / TILE, 2), 256, 0, stream>>>(
      featb, wvt, HD, HD, HD, MSEL, bv, nullptr, avr, nullptr, HD2,
      nullptr, wut, bu, aur, nullptr);

  // 8) logits + per-row feat.Wc
  attlogit_k<<<(MSEL + 3) / 4, 256, 0, stream>>>(avr, aur, featf, Wa, Wc, zbuf, gbuf, MSEL);

  // 9) softmax + outputs
  final_k<<<1, 1024, 0, stream>>>(zbuf, gbuf, bc, out, MSEL);
}